// Round 6
// baseline (10237.396 us; speedup 1.0000x reference)
//
#include <hip/hip_runtime.h>
#include <cstdint>
#include <cstddef>

#define TT 2048
#define VV 32000
#define EE 512
#define HH 1024

typedef __bf16 bf16x8 __attribute__((ext_vector_type(8)));
typedef float f32x4 __attribute__((ext_vector_type(4)));
typedef unsigned uint32x4 __attribute__((ext_vector_type(4)));

static __device__ __forceinline__ unsigned short f2b(float f) {
    unsigned u = __float_as_uint(f);
    unsigned r = (u + 0x7fffu + ((u >> 16) & 1u)) >> 16;   // RNE
    return (unsigned short)r;
}
static __device__ __forceinline__ float sigm(float x) {
    return __builtin_amdgcn_rcpf(1.f + __expf(-x));
}
static __device__ __forceinline__ float tanh_s(float x) {
    float a = fabsf(x);
    float e = __expf(-2.f * a);
    float r = (1.f - e) * __builtin_amdgcn_rcpf(1.f + e);
    return copysignf(r, x);
}
static __device__ __forceinline__ void flag_set(int* f, int v) {
    __hip_atomic_store(f, v, __ATOMIC_RELEASE, __HIP_MEMORY_SCOPE_WORKGROUP);
}
static __device__ __forceinline__ void flag_spin(int* f, int want) {
    while (__hip_atomic_load(f, __ATOMIC_ACQUIRE, __HIP_MEMORY_SCOPE_WORKGROUP) < want) {}
}

// ---------------- embedding gather -> bf16 ----------------
__global__ __launch_bounds__(128) void embed_kernel(
    const int* __restrict__ tok, const float* __restrict__ emb,
    unsigned short* __restrict__ xs_b) {
    int t = blockIdx.x;
    int e4 = threadIdx.x;
    const float4* src = (const float4*)(emb + (size_t)tok[t] * EE);
    float4 v = src[e4];
    ushort4 o;
    o.x = f2b(v.x); o.y = f2b(v.y); o.z = f2b(v.z); o.w = f2b(v.w);
    ((ushort4*)(xs_b + (size_t)t * EE))[e4] = o;
}

// ---------------- generic f32 -> bf16 ----------------
__global__ __launch_bounds__(256) void f32_to_bf16(
    const float* __restrict__ in, unsigned short* __restrict__ out, long n4) {
    long i = (long)blockIdx.x * blockDim.x + threadIdx.x;
    long stride = (long)gridDim.x * blockDim.x;
    for (; i < n4; i += stride) {
        float4 v = ((const float4*)in)[i];
        ushort4 o;
        o.x = f2b(v.x); o.y = f2b(v.y); o.z = f2b(v.z); o.w = f2b(v.w);
        ((ushort4*)out)[i] = o;
    }
}

// ---------------- bf16 MFMA GEMM: C[M,N] = A[M,K] * B[N,K]^T + bias ----------------
__global__ __launch_bounds__(256) void gemm_bf16_nt(
    const unsigned short* __restrict__ A,   // [M][K] bf16 bits
    const unsigned short* __restrict__ B,   // [N][K] bf16 bits
    const float* __restrict__ bias1,        // [N] or null
    const float* __restrict__ bias2,        // [N] or null
    float* __restrict__ C,                  // [M][N]
    int K, int N) {
    __shared__ unsigned short ldsA[128 * 64];
    __shared__ unsigned short ldsB[128 * 64];
    const int tid = threadIdx.x;
    const int l = tid & 63;
    const int w = tid >> 6;
    const int wm = (w >> 1) * 64;
    const int wn = (w & 1) * 64;
    const int bm = blockIdx.y, bn = blockIdx.x;
    const size_t a_base = (size_t)bm * 128 * K;
    const size_t b_base = (size_t)bn * 128 * K;
    const int srow = tid >> 3;
    const int skc = tid & 7;

    f32x4 acc[4][4];
    for (int i = 0; i < 4; ++i)
        for (int j = 0; j < 4; ++j)
            acc[i][j] = (f32x4){0.f, 0.f, 0.f, 0.f};

    for (int kt = 0; kt < K; kt += 64) {
        uint4 av[4], bv[4];
#pragma unroll
        for (int i = 0; i < 4; ++i) {
            int row = srow + i * 32;
            av[i] = ((const uint4*)(A + a_base + (size_t)row * K + kt))[skc];
            bv[i] = ((const uint4*)(B + b_base + (size_t)row * K + kt))[skc];
        }
        __syncthreads();
#pragma unroll
        for (int i = 0; i < 4; ++i) {
            int row = srow + i * 32;
            int off = row * 128 + ((skc * 16) ^ ((row & 7) << 4));
            *(uint4*)((char*)ldsA + off) = av[i];
            *(uint4*)((char*)ldsB + off) = bv[i];
        }
        __syncthreads();
#pragma unroll
        for (int ks = 0; ks < 2; ++ks) {
            bf16x8 af[4], bfr[4];
            int kb = ks * 64 + (l >> 4) * 16;
#pragma unroll
            for (int f = 0; f < 4; ++f) {
                int ar = wm + f * 16 + (l & 15);
                af[f] = *(const bf16x8*)((const char*)ldsA + ar * 128 + (kb ^ ((ar & 7) << 4)));
                int br = wn + f * 16 + (l & 15);
                bfr[f] = *(const bf16x8*)((const char*)ldsB + br * 128 + (kb ^ ((br & 7) << 4)));
            }
#pragma unroll
            for (int fm = 0; fm < 4; ++fm)
#pragma unroll
                for (int fn = 0; fn < 4; ++fn)
                    acc[fm][fn] = __builtin_amdgcn_mfma_f32_16x16x32_bf16(
                        af[fm], bfr[fn], acc[fm][fn], 0, 0, 0);
        }
    }
    const int r0 = (l >> 4) * 4, cn = (l & 15);
#pragma unroll
    for (int fm = 0; fm < 4; ++fm)
#pragma unroll
        for (int fn = 0; fn < 4; ++fn) {
            int col = bn * 128 + wn + fn * 16 + cn;
            float bb = (bias1 ? bias1[col] : 0.f) + (bias2 ? bias2[col] : 0.f);
#pragma unroll
            for (int r = 0; r < 4; ++r) {
                int rowg = bm * 128 + wm + fm * 16 + r0 + r;
                C[(size_t)rowg * N + col] = acc[fm][fn][r] + bb;
            }
        }
}

// ======== macros for the recurrence kernel ========
// packed comm word: {tag16 (hi) | bf16 h bits (lo)}
#define BFL(P, E) __uint_as_float((P)[E] << 16)
#define CHK4(P, W) ((((P)[0] >> 16) == (W)) & (((P)[1] >> 16) == (W)) & \
                    (((P)[2] >> 16) == (W)) & (((P)[3] >> 16) == (W)))
// 4x dwordx4 LLC-bypass poll; lane covers elements {4l, 256+4l, 512+4l, 768+4l}..+3
#define POLL4(P0, P1, P2, P3, BASE, WANT)                                   \
    for (;;) {                                                              \
        asm volatile(                                                       \
            "global_load_dwordx4 %0, %4, off sc0 sc1\n\t"                   \
            "global_load_dwordx4 %1, %5, off sc0 sc1\n\t"                   \
            "global_load_dwordx4 %2, %6, off sc0 sc1\n\t"                   \
            "global_load_dwordx4 %3, %7, off sc0 sc1\n\t"                   \
            "s_waitcnt vmcnt(0)"                                            \
            : "=&v"(P0), "=&v"(P1), "=&v"(P2), "=&v"(P3)                    \
            : "v"((BASE) + 4 * lane), "v"((BASE) + 4 * lane + 256),         \
              "v"((BASE) + 4 * lane + 512), "v"((BASE) + 4 * lane + 768)    \
            : "memory");                                                    \
        if (CHK4(P0, WANT) & CHK4(P1, WANT) & CHK4(P2, WANT) & CHK4(P3, WANT)) break; \
        __builtin_amdgcn_s_sleep(1);                                        \
    }
#define PUBLISH(PTR, PK)                                                    \
    asm volatile("global_store_dword %0, %1, off sc0 sc1"                   \
                 :: "v"(PTR), "v"(PK) : "memory")
#define RED(D) { D += __shfl_xor(D, 32); D += __shfl_xor(D, 16);            \
                 D += __shfl_xor(D, 8);  D += __shfl_xor(D, 4);             \
                 D += __shfl_xor(D, 2);  D += __shfl_xor(D, 1); }
#define STAGE(BUF, P0, P1, P2, P3) {                                        \
    float4 f_;                                                              \
    f_.x = BFL(P0,0); f_.y = BFL(P0,1); f_.z = BFL(P0,2); f_.w = BFL(P0,3); \
    *(float4*)&(BUF)[4 * lane] = f_;                                        \
    f_.x = BFL(P1,0); f_.y = BFL(P1,1); f_.z = BFL(P1,2); f_.w = BFL(P1,3); \
    *(float4*)&(BUF)[256 + 4 * lane] = f_;                                  \
    f_.x = BFL(P2,0); f_.y = BFL(P2,1); f_.z = BFL(P2,2); f_.w = BFL(P2,3); \
    *(float4*)&(BUF)[512 + 4 * lane] = f_;                                  \
    f_.x = BFL(P3,0); f_.y = BFL(P3,1); f_.z = BFL(P3,2); f_.w = BFL(P3,3); \
    *(float4*)&(BUF)[768 + 4 * lane] = f_; }
#define LDSREAD(H0, H1, H2, H3, BUF) {                                      \
    H0 = *(const float4*)&(BUF)[4 * lane];                                  \
    H1 = *(const float4*)&(BUF)[256 + 4 * lane];                            \
    H2 = *(const float4*)&(BUF)[512 + 4 * lane];                            \
    H3 = *(const float4*)&(BUF)[768 + 4 * lane]; }

// ---- register-resident weight row: 16 named scalars per 64 owned elems ----
#define ROW_DECL(P) float P##_0,P##_1,P##_2,P##_3,P##_4,P##_5,P##_6,P##_7,  \
                          P##_8,P##_9,P##_a,P##_b,P##_c,P##_d,P##_e,P##_f
#define ROW_LOAD(P, RP) {                                                   \
    float4 t0_ = *(const float4*)(RP);                                      \
    float4 t1_ = *(const float4*)((RP) + 256);                              \
    float4 t2_ = *(const float4*)((RP) + 512);                              \
    float4 t3_ = *(const float4*)((RP) + 768);                              \
    P##_0=t0_.x; P##_1=t0_.y; P##_2=t0_.z; P##_3=t0_.w;                     \
    P##_4=t1_.x; P##_5=t1_.y; P##_6=t1_.z; P##_7=t1_.w;                     \
    P##_8=t2_.x; P##_9=t2_.y; P##_a=t2_.z; P##_b=t2_.w;                     \
    P##_c=t3_.x; P##_d=t3_.y; P##_e=t3_.z; P##_f=t3_.w; }
#define ROW_PIN(P) asm volatile("" :                                        \
    "+v"(P##_0),"+v"(P##_1),"+v"(P##_2),"+v"(P##_3),                        \
    "+v"(P##_4),"+v"(P##_5),"+v"(P##_6),"+v"(P##_7),                        \
    "+v"(P##_8),"+v"(P##_9),"+v"(P##_a),"+v"(P##_b),                        \
    "+v"(P##_c),"+v"(P##_d),"+v"(P##_e),"+v"(P##_f))
#define ROW_DOTF(D, P, H0, H1, H2, H3) {                                    \
    D=__builtin_fmaf(P##_0,(H0).x,D); D=__builtin_fmaf(P##_1,(H0).y,D);     \
    D=__builtin_fmaf(P##_2,(H0).z,D); D=__builtin_fmaf(P##_3,(H0).w,D);     \
    D=__builtin_fmaf(P##_4,(H1).x,D); D=__builtin_fmaf(P##_5,(H1).y,D);     \
    D=__builtin_fmaf(P##_6,(H1).z,D); D=__builtin_fmaf(P##_7,(H1).w,D);     \
    D=__builtin_fmaf(P##_8,(H2).x,D); D=__builtin_fmaf(P##_9,(H2).y,D);     \
    D=__builtin_fmaf(P##_a,(H2).z,D); D=__builtin_fmaf(P##_b,(H2).w,D);     \
    D=__builtin_fmaf(P##_c,(H3).x,D); D=__builtin_fmaf(P##_d,(H3).y,D);     \
    D=__builtin_fmaf(P##_e,(H3).z,D); D=__builtin_fmaf(P##_f,(H3).w,D); }
#define ROW_DOTP(D, P, Q0, Q1, Q2, Q3) {                                    \
    D=__builtin_fmaf(P##_0,BFL(Q0,0),D); D=__builtin_fmaf(P##_1,BFL(Q0,1),D); \
    D=__builtin_fmaf(P##_2,BFL(Q0,2),D); D=__builtin_fmaf(P##_3,BFL(Q0,3),D); \
    D=__builtin_fmaf(P##_4,BFL(Q1,0),D); D=__builtin_fmaf(P##_5,BFL(Q1,1),D); \
    D=__builtin_fmaf(P##_6,BFL(Q1,2),D); D=__builtin_fmaf(P##_7,BFL(Q1,3),D); \
    D=__builtin_fmaf(P##_8,BFL(Q2,0),D); D=__builtin_fmaf(P##_9,BFL(Q2,1),D); \
    D=__builtin_fmaf(P##_a,BFL(Q2,2),D); D=__builtin_fmaf(P##_b,BFL(Q2,3),D); \
    D=__builtin_fmaf(P##_c,BFL(Q3,0),D); D=__builtin_fmaf(P##_d,BFL(Q3,1),D); \
    D=__builtin_fmaf(P##_e,BFL(Q3,2),D); D=__builtin_fmaf(P##_f,BFL(Q3,3),D); }

// ---------------- fused 2-layer pipelined LSTM recurrence ----------------
// 256 blocks x 512 threads (1 block/CU). Blocks 0..127: layer 0; 128..255:
// layer 1 (1 step behind via full-history hist0). Wave wv owns unit
// j = bid*8+wv; weights fp32 in NAMED pinned scalar VGPRs. Lane l owns
// k = {4l..4l+3} + 256q. Stager wave(s) poll packed global vector
// (LLC-bypass dwordx4), stage f32 to LDS conflict-free, publish LDS flag;
// consumers spin flag + ds_read_b128. No __syncthreads in the loop:
// distance-2 overwrite safety is enforced by the stagers' own global polls
// (hist tags include this block's own units).
__global__ __launch_bounds__(512, 2) void lstm_fused(
    const float* __restrict__ Whh0,           // [4H][H]
    const float* __restrict__ pre0,           // [T][4H] (x-proj + both biases)
    const float* __restrict__ Wih1,           // [4H][H]
    const float* __restrict__ Whh1,           // [4H][H]
    const float* __restrict__ bih1,           // [4H]
    const float* __restrict__ bhh1,           // [4H]
    unsigned* __restrict__ hist0,             // [T][H] packed h0 history
    unsigned* __restrict__ hist1,             // [T][H] packed h1 history
    unsigned short* __restrict__ y1b,         // [T][H] bf16 layer-1 output
    float* __restrict__ hfb,                  // out + T*V      (h stack [2][H])
    float* __restrict__ cfb) {                // out + T*V + 2H (c stack [2][H])
    const int wv   = threadIdx.x >> 6;
    const int lane = threadIdx.x & 63;

    __shared__ float hS[4][HH];               // [0/1]: A parity, [2/3]: B parity
    __shared__ int flagA, flagB;
    if (threadIdx.x == 0) { flagA = 0; flagB = 0; }
    __syncthreads();

    uint32x4 p0, p1, p2, p3, q0, q1, q2, q3;
    float4 h0_, h1_, h2_, h3_;

    if (blockIdx.x < 128) {
        // ================= layer 0 =================
        const int j = blockIdx.x * 8 + wv;
        ROW_DECL(wI); ROW_DECL(wF); ROW_DECL(wG); ROW_DECL(wO);
        ROW_LOAD(wI, Whh0 + (size_t)(0 * HH + j) * HH + 4 * lane);
        ROW_LOAD(wF, Whh0 + (size_t)(1 * HH + j) * HH + 4 * lane);
        ROW_LOAD(wG, Whh0 + (size_t)(2 * HH + j) * HH + 4 * lane);
        ROW_LOAD(wO, Whh0 + (size_t)(3 * HH + j) * HH + 4 * lane);
        ROW_PIN(wI); ROW_PIN(wF); ROW_PIN(wG); ROW_PIN(wO);

        float c = 0.f;
        float px0 = pre0[0 * HH + j], px1 = pre0[1 * HH + j];
        float px2 = pre0[2 * HH + j], px3 = pre0[3 * HH + j];

        for (int t = 0; t < TT; ++t) {
            float nx0 = 0.f, nx1 = 0.f, nx2 = 0.f, nx3 = 0.f;
            if (t + 1 < TT) {
                const float* pp = pre0 + (size_t)(t + 1) * 4 * HH + j;
                nx0 = pp[0]; nx1 = pp[HH]; nx2 = pp[2 * HH]; nx3 = pp[3 * HH];
            }
            const int par = t & 1;
            float d0 = 0.f, d1 = 0.f, d2 = 0.f, d3 = 0.f;
            if (wv == 0) {
                if (t > 0) {
                    const unsigned want = (unsigned)t;
                    POLL4(p0, p1, p2, p3, hist0 + (size_t)(t - 1) * HH, want);
                    STAGE(hS[par], p0, p1, p2, p3);
                }
                flag_set(&flagA, t + 1);
                if (t > 0) {
                    ROW_DOTP(d0, wI, p0, p1, p2, p3);
                    ROW_DOTP(d1, wF, p0, p1, p2, p3);
                    ROW_DOTP(d2, wG, p0, p1, p2, p3);
                    ROW_DOTP(d3, wO, p0, p1, p2, p3);
                }
            } else {
                flag_spin(&flagA, t + 1);
                if (t > 0) {
                    LDSREAD(h0_, h1_, h2_, h3_, hS[par]);
                    ROW_DOTF(d0, wI, h0_, h1_, h2_, h3_);
                    ROW_DOTF(d1, wF, h0_, h1_, h2_, h3_);
                    ROW_DOTF(d2, wG, h0_, h1_, h2_, h3_);
                    ROW_DOTF(d3, wO, h0_, h1_, h2_, h3_);
                }
            }
            if (t > 0) { RED(d0); RED(d1); RED(d2); RED(d3); }
            float i_ = sigm(px0 + d0), f_ = sigm(px1 + d1);
            float g_ = tanh_s(px2 + d2), o_ = sigm(px3 + d3);
            c = f_ * c + i_ * g_;
            float h = o_ * tanh_s(c);
            if (lane == 0) {
                unsigned pack = ((unsigned)(t + 1) << 16) | (unsigned)f2b(h);
                PUBLISH(hist0 + (size_t)t * HH + j, pack);
                if (t == TT - 1) { hfb[j] = h; cfb[j] = c; }
            }
            px0 = nx0; px1 = nx1; px2 = nx2; px3 = nx3;
        }
    } else {
        // ================= layer 1 (1 step behind) =================
        const int j = (blockIdx.x - 128) * 8 + wv;
        ROW_DECL(iI); ROW_DECL(iF); ROW_DECL(iG); ROW_DECL(iO);
        ROW_DECL(hI); ROW_DECL(hF); ROW_DECL(hG); ROW_DECL(hO);
        ROW_LOAD(iI, Wih1 + (size_t)(0 * HH + j) * HH + 4 * lane);
        ROW_LOAD(iF, Wih1 + (size_t)(1 * HH + j) * HH + 4 * lane);
        ROW_LOAD(iG, Wih1 + (size_t)(2 * HH + j) * HH + 4 * lane);
        ROW_LOAD(iO, Wih1 + (size_t)(3 * HH + j) * HH + 4 * lane);
        ROW_LOAD(hI, Whh1 + (size_t)(0 * HH + j) * HH + 4 * lane);
        ROW_LOAD(hF, Whh1 + (size_t)(1 * HH + j) * HH + 4 * lane);
        ROW_LOAD(hG, Whh1 + (size_t)(2 * HH + j) * HH + 4 * lane);
        ROW_LOAD(hO, Whh1 + (size_t)(3 * HH + j) * HH + 4 * lane);
        ROW_PIN(iI); ROW_PIN(iF); ROW_PIN(iG); ROW_PIN(iO);
        ROW_PIN(hI); ROW_PIN(hF); ROW_PIN(hG); ROW_PIN(hO);
        float bs0 = bih1[0 * HH + j] + bhh1[0 * HH + j];
        float bs1 = bih1[1 * HH + j] + bhh1[1 * HH + j];
        float bs2 = bih1[2 * HH + j] + bhh1[2 * HH + j];
        float bs3 = bih1[3 * HH + j] + bhh1[3 * HH + j];

        float c = 0.f;
        for (int t = 0; t < TT; ++t) {
            const int par = t & 1;
            float d0 = 0.f, d1 = 0.f, d2 = 0.f, d3 = 0.f;
            if (wv == 0) {
                // A-stager: h0_t (tag t+1)
                const unsigned want = (unsigned)(t + 1);
                POLL4(p0, p1, p2, p3, hist0 + (size_t)t * HH, want);
                STAGE(hS[par], p0, p1, p2, p3);
                flag_set(&flagA, t + 1);
                ROW_DOTP(d0, iI, p0, p1, p2, p3);
                ROW_DOTP(d1, iF, p0, p1, p2, p3);
                ROW_DOTP(d2, iG, p0, p1, p2, p3);
                ROW_DOTP(d3, iO, p0, p1, p2, p3);
                flag_spin(&flagB, t + 1);
                if (t > 0) {
                    LDSREAD(h0_, h1_, h2_, h3_, hS[2 + par]);
                    ROW_DOTF(d0, hI, h0_, h1_, h2_, h3_);
                    ROW_DOTF(d1, hF, h0_, h1_, h2_, h3_);
                    ROW_DOTF(d2, hG, h0_, h1_, h2_, h3_);
                    ROW_DOTF(d3, hO, h0_, h1_, h2_, h3_);
                }
            } else if (wv == 1) {
                // B-stager: h1_{t-1} (tag t)
                if (t > 0) {
                    const unsigned want = (unsigned)t;
                    POLL4(q0, q1, q2, q3, hist1 + (size_t)(t - 1) * HH, want);
                    STAGE(hS[2 + par], q0, q1, q2, q3);
                }
                flag_set(&flagB, t + 1);
                flag_spin(&flagA, t + 1);
                LDSREAD(h0_, h1_, h2_, h3_, hS[par]);
                ROW_DOTF(d0, iI, h0_, h1_, h2_, h3_);
                ROW_DOTF(d1, iF, h0_, h1_, h2_, h3_);
                ROW_DOTF(d2, iG, h0_, h1_, h2_, h3_);
                ROW_DOTF(d3, iO, h0_, h1_, h2_, h3_);
                if (t > 0) {
                    ROW_DOTP(d0, hI, q0, q1, q2, q3);
                    ROW_DOTP(d1, hF, q0, q1, q2, q3);
                    ROW_DOTP(d2, hG, q0, q1, q2, q3);
                    ROW_DOTP(d3, hO, q0, q1, q2, q3);
                }
            } else {
                flag_spin(&flagA, t + 1);
                LDSREAD(h0_, h1_, h2_, h3_, hS[par]);
                ROW_DOTF(d0, iI, h0_, h1_, h2_, h3_);
                ROW_DOTF(d1, iF, h0_, h1_, h2_, h3_);
                ROW_DOTF(d2, iG, h0_, h1_, h2_, h3_);
                ROW_DOTF(d3, iO, h0_, h1_, h2_, h3_);
                flag_spin(&flagB, t + 1);
                if (t > 0) {
                    LDSREAD(h0_, h1_, h2_, h3_, hS[2 + par]);
                    ROW_DOTF(d0, hI, h0_, h1_, h2_, h3_);
                    ROW_DOTF(d1, hF, h0_, h1_, h2_, h3_);
                    ROW_DOTF(d2, hG, h0_, h1_, h2_, h3_);
                    ROW_DOTF(d3, hO, h0_, h1_, h2_, h3_);
                }
            }
            RED(d0); RED(d1); RED(d2); RED(d3);
            float i_ = sigm(bs0 + d0), f_ = sigm(bs1 + d1);
            float g_ = tanh_s(bs2 + d2), o_ = sigm(bs3 + d3);
            c = f_ * c + i_ * g_;
            float h = o_ * tanh_s(c);
            if (lane == 0) {
                unsigned short hb16 = f2b(h);
                unsigned pack = ((unsigned)(t + 1) << 16) | (unsigned)hb16;
                PUBLISH(hist1 + (size_t)t * HH + j, pack);
                y1b[(size_t)t * HH + j] = hb16;
                if (t == TT - 1) { hfb[HH + j] = h; cfb[HH + j] = c; }
            }
        }
    }
}

// ---------------- row softmax over V=32000, in place ----------------
__global__ __launch_bounds__(256) void softmax_kernel(float* __restrict__ data) {
    const int row = blockIdx.x;
    const int tid = threadIdx.x;
    float* p = data + (size_t)row * VV;
    float m = -1e30f, s = 0.f;
    for (int i = tid * 4; i < VV; i += 1024) {
        float4 v = *(const float4*)(p + i);
        float x[4] = {v.x, v.y, v.z, v.w};
#pragma unroll
        for (int q = 0; q < 4; ++q) {
            float xv = x[q];
            if (xv > m) { s = s * __expf(m - xv) + 1.f; m = xv; }
            else s += __expf(xv - m);
        }
    }
#pragma unroll
    for (int off = 32; off; off >>= 1) {
        float mo = __shfl_xor(m, off);
        float so = __shfl_xor(s, off);
        float mn = fmaxf(m, mo);
        s = s * __expf(m - mn) + so * __expf(mo - mn);
        m = mn;
    }
    __shared__ float sm[4], ss[4];
    int wvv = tid >> 6;
    if ((tid & 63) == 0) { sm[wvv] = m; ss[wvv] = s; }
    __syncthreads();
    float M = fmaxf(fmaxf(sm[0], sm[1]), fmaxf(sm[2], sm[3]));
    float S = ss[0] * __expf(sm[0] - M) + ss[1] * __expf(sm[1] - M) +
              ss[2] * __expf(sm[2] - M) + ss[3] * __expf(sm[3] - M);
    float inv = 1.f / S;
    for (int i = tid * 4; i < VV; i += 1024) {
        float4 v = *(const float4*)(p + i);
        v.x = __expf(v.x - M) * inv;
        v.y = __expf(v.y - M) * inv;
        v.z = __expf(v.z - M) * inv;
        v.w = __expf(v.w - M) * inv;
        *(float4*)(p + i) = v;
    }
}

extern "C" void kernel_launch(void* const* d_in, const int* in_sizes, int n_in,
                              void* d_out, int out_size, void* d_ws, size_t ws_size,
                              hipStream_t stream) {
    const int*   inputs = (const int*)d_in[0];
    const float* emb    = (const float*)d_in[1];
    const float* w_ih0  = (const float*)d_in[2];
    const float* w_hh0  = (const float*)d_in[3];
    const float* b_ih0  = (const float*)d_in[4];
    const float* b_hh0  = (const float*)d_in[5];
    const float* w_ih1  = (const float*)d_in[6];
    const float* w_hh1  = (const float*)d_in[7];
    const float* b_ih1  = (const float*)d_in[8];
    const float* b_hh1  = (const float*)d_in[9];
    const float* w_out  = (const float*)d_in[10];
    const float* b_out  = (const float*)d_in[11];
    float* out = (float*)d_out;

    char* ws = (char*)d_ws;
    size_t off = 0;
    auto alloc = [&](size_t bytes) -> void* {
        void* p = ws + off;
        off += (bytes + 255) & ~(size_t)255;
        return p;
    };
    float* pre0          = (float*)alloc((size_t)TT * 4 * HH * 4);
    unsigned short* xsb  = (unsigned short*)alloc((size_t)TT * EE * 2);
    unsigned short* w0b  = (unsigned short*)alloc((size_t)4 * HH * EE * 2);
    unsigned short* wob  = (unsigned short*)alloc((size_t)VV * HH * 2);
    unsigned short* y1b  = (unsigned short*)alloc((size_t)TT * HH * 2);
    unsigned* hist0      = (unsigned*)alloc((size_t)TT * HH * 4);
    unsigned* hist1      = (unsigned*)alloc((size_t)TT * HH * 4);
    if (off > ws_size) return;

    (void)hipMemsetAsync(hist0, 0, (size_t)TT * HH * 4, stream);
    (void)hipMemsetAsync(hist1, 0, (size_t)TT * HH * 4, stream);

    embed_kernel<<<TT, 128, 0, stream>>>(inputs, emb, xsb);
    f32_to_bf16<<<1024, 256, 0, stream>>>(w_ih0, w0b, (long)4 * HH * EE / 4);
    f32_to_bf16<<<2048, 256, 0, stream>>>(w_out, wob, (long)VV * HH / 4);

    // pre0 = xs @ w_ih0^T + b_ih0 + b_hh0
    gemm_bf16_nt<<<dim3(4 * HH / 128, TT / 128), 256, 0, stream>>>(
        xsb, w0b, b_ih0, b_hh0, pre0, EE, 4 * HH);

    // fused pipelined 2-layer recurrence
    lstm_fused<<<256, 512, 0, stream>>>(
        w_hh0, pre0, w_ih1, w_hh1, b_ih1, b_hh1,
        hist0, hist1, y1b,
        out + (size_t)TT * VV, out + (size_t)TT * VV + 2 * HH);

    // logits = ys1 @ w_out^T + b_out  (into d_out, softmax in place after)
    gemm_bf16_nt<<<dim3(VV / 128, TT / 128), 256, 0, stream>>>(
        y1b, wob, b_out, nullptr, out, HH, VV);
    softmax_kernel<<<TT, 256, 0, stream>>>(out);
}

// Round 7
// 9695.048 us; speedup vs baseline: 1.0559x; 1.0559x over previous
//
#include <hip/hip_runtime.h>
#include <cstdint>
#include <cstddef>

#define TT 2048
#define VV 32000
#define EE 512
#define HH 1024

typedef __bf16 bf16x8 __attribute__((ext_vector_type(8)));
typedef float f32x4 __attribute__((ext_vector_type(4)));
typedef unsigned uint32x4 __attribute__((ext_vector_type(4)));

static __device__ __forceinline__ unsigned short f2b(float f) {
    unsigned u = __float_as_uint(f);
    unsigned r = (u + 0x7fffu + ((u >> 16) & 1u)) >> 16;   // RNE
    return (unsigned short)r;
}
static __device__ __forceinline__ float sigm(float x) {
    return __builtin_amdgcn_rcpf(1.f + __expf(-x));
}
static __device__ __forceinline__ float tanh_s(float x) {
    float a = fabsf(x);
    float e = __expf(-2.f * a);
    float r = (1.f - e) * __builtin_amdgcn_rcpf(1.f + e);
    return copysignf(r, x);
}
static __device__ __forceinline__ void flag_set(int* f, int v) {
    __hip_atomic_store(f, v, __ATOMIC_RELEASE, __HIP_MEMORY_SCOPE_WORKGROUP);
}
static __device__ __forceinline__ void flag_spin(int* f, int want) {
    while (__hip_atomic_load(f, __ATOMIC_ACQUIRE, __HIP_MEMORY_SCOPE_WORKGROUP) < want) {}
}

// ---------------- embedding gather -> bf16 ----------------
__global__ __launch_bounds__(128) void embed_kernel(
    const int* __restrict__ tok, const float* __restrict__ emb,
    unsigned short* __restrict__ xs_b) {
    int t = blockIdx.x;
    int e4 = threadIdx.x;
    const float4* src = (const float4*)(emb + (size_t)tok[t] * EE);
    float4 v = src[e4];
    ushort4 o;
    o.x = f2b(v.x); o.y = f2b(v.y); o.z = f2b(v.z); o.w = f2b(v.w);
    ((ushort4*)(xs_b + (size_t)t * EE))[e4] = o;
}

// ---------------- generic f32 -> bf16 ----------------
__global__ __launch_bounds__(256) void f32_to_bf16(
    const float* __restrict__ in, unsigned short* __restrict__ out, long n4) {
    long i = (long)blockIdx.x * blockDim.x + threadIdx.x;
    long stride = (long)gridDim.x * blockDim.x;
    for (; i < n4; i += stride) {
        float4 v = ((const float4*)in)[i];
        ushort4 o;
        o.x = f2b(v.x); o.y = f2b(v.y); o.z = f2b(v.z); o.w = f2b(v.w);
        ((ushort4*)out)[i] = o;
    }
}

// ---------------- bf16 MFMA GEMM: C[M,N] = A[M,K] * B[N,K]^T + bias ----------------
__global__ __launch_bounds__(256) void gemm_bf16_nt(
    const unsigned short* __restrict__ A,   // [M][K] bf16 bits
    const unsigned short* __restrict__ B,   // [N][K] bf16 bits
    const float* __restrict__ bias1,        // [N] or null
    const float* __restrict__ bias2,        // [N] or null
    float* __restrict__ C,                  // [M][N]
    int K, int N) {
    __shared__ unsigned short ldsA[128 * 64];
    __shared__ unsigned short ldsB[128 * 64];
    const int tid = threadIdx.x;
    const int l = tid & 63;
    const int w = tid >> 6;
    const int wm = (w >> 1) * 64;
    const int wn = (w & 1) * 64;
    const int bm = blockIdx.y, bn = blockIdx.x;
    const size_t a_base = (size_t)bm * 128 * K;
    const size_t b_base = (size_t)bn * 128 * K;
    const int srow = tid >> 3;
    const int skc = tid & 7;

    f32x4 acc[4][4];
    for (int i = 0; i < 4; ++i)
        for (int j = 0; j < 4; ++j)
            acc[i][j] = (f32x4){0.f, 0.f, 0.f, 0.f};

    for (int kt = 0; kt < K; kt += 64) {
        uint4 av[4], bv[4];
#pragma unroll
        for (int i = 0; i < 4; ++i) {
            int row = srow + i * 32;
            av[i] = ((const uint4*)(A + a_base + (size_t)row * K + kt))[skc];
            bv[i] = ((const uint4*)(B + b_base + (size_t)row * K + kt))[skc];
        }
        __syncthreads();
#pragma unroll
        for (int i = 0; i < 4; ++i) {
            int row = srow + i * 32;
            int off = row * 128 + ((skc * 16) ^ ((row & 7) << 4));
            *(uint4*)((char*)ldsA + off) = av[i];
            *(uint4*)((char*)ldsB + off) = bv[i];
        }
        __syncthreads();
#pragma unroll
        for (int ks = 0; ks < 2; ++ks) {
            bf16x8 af[4], bfr[4];
            int kb = ks * 64 + (l >> 4) * 16;
#pragma unroll
            for (int f = 0; f < 4; ++f) {
                int ar = wm + f * 16 + (l & 15);
                af[f] = *(const bf16x8*)((const char*)ldsA + ar * 128 + (kb ^ ((ar & 7) << 4)));
                int br = wn + f * 16 + (l & 15);
                bfr[f] = *(const bf16x8*)((const char*)ldsB + br * 128 + (kb ^ ((br & 7) << 4)));
            }
#pragma unroll
            for (int fm = 0; fm < 4; ++fm)
#pragma unroll
                for (int fn = 0; fn < 4; ++fn)
                    acc[fm][fn] = __builtin_amdgcn_mfma_f32_16x16x32_bf16(
                        af[fm], bfr[fn], acc[fm][fn], 0, 0, 0);
        }
    }
    const int r0 = (l >> 4) * 4, cn = (l & 15);
#pragma unroll
    for (int fm = 0; fm < 4; ++fm)
#pragma unroll
        for (int fn = 0; fn < 4; ++fn) {
            int col = bn * 128 + wn + fn * 16 + cn;
            float bb = (bias1 ? bias1[col] : 0.f) + (bias2 ? bias2[col] : 0.f);
#pragma unroll
            for (int r = 0; r < 4; ++r) {
                int rowg = bm * 128 + wm + fm * 16 + r0 + r;
                C[(size_t)rowg * N + col] = acc[fm][fn][r] + bb;
            }
        }
}

// ======== macros for the recurrence kernel ========
// packed comm word: {tag16 (hi) | bf16 h bits (lo)}
#define BFL(P, E) __uint_as_float((P)[E] << 16)
#define CHK4(P, W) ((((P)[0] >> 16) == (W)) & (((P)[1] >> 16) == (W)) & \
                    (((P)[2] >> 16) == (W)) & (((P)[3] >> 16) == (W)))
// 4x dwordx4 LLC-bypass poll; lane covers elements {4l, 256+4l, 512+4l, 768+4l}..+3
#define POLL4(P0, P1, P2, P3, BASE, WANT)                                   \
    for (;;) {                                                              \
        asm volatile(                                                       \
            "global_load_dwordx4 %0, %4, off sc0 sc1\n\t"                   \
            "global_load_dwordx4 %1, %5, off sc0 sc1\n\t"                   \
            "global_load_dwordx4 %2, %6, off sc0 sc1\n\t"                   \
            "global_load_dwordx4 %3, %7, off sc0 sc1\n\t"                   \
            "s_waitcnt vmcnt(0)"                                            \
            : "=&v"(P0), "=&v"(P1), "=&v"(P2), "=&v"(P3)                    \
            : "v"((BASE) + 4 * lane), "v"((BASE) + 4 * lane + 256),         \
              "v"((BASE) + 4 * lane + 512), "v"((BASE) + 4 * lane + 768)    \
            : "memory");                                                    \
        if (CHK4(P0, WANT) & CHK4(P1, WANT) & CHK4(P2, WANT) & CHK4(P3, WANT)) break; \
        __builtin_amdgcn_s_sleep(1);                                        \
    }
#define PUBLISH(PTR, PK)                                                    \
    asm volatile("global_store_dword %0, %1, off sc0 sc1"                   \
                 :: "v"(PTR), "v"(PK) : "memory")
#define RED(D) { D += __shfl_xor(D, 32); D += __shfl_xor(D, 16);            \
                 D += __shfl_xor(D, 8);  D += __shfl_xor(D, 4);             \
                 D += __shfl_xor(D, 2);  D += __shfl_xor(D, 1); }
#define STAGE(BUF, P0, P1, P2, P3) {                                        \
    float4 f_;                                                              \
    f_.x = BFL(P0,0); f_.y = BFL(P0,1); f_.z = BFL(P0,2); f_.w = BFL(P0,3); \
    *(float4*)&(BUF)[4 * lane] = f_;                                        \
    f_.x = BFL(P1,0); f_.y = BFL(P1,1); f_.z = BFL(P1,2); f_.w = BFL(P1,3); \
    *(float4*)&(BUF)[256 + 4 * lane] = f_;                                  \
    f_.x = BFL(P2,0); f_.y = BFL(P2,1); f_.z = BFL(P2,2); f_.w = BFL(P2,3); \
    *(float4*)&(BUF)[512 + 4 * lane] = f_;                                  \
    f_.x = BFL(P3,0); f_.y = BFL(P3,1); f_.z = BFL(P3,2); f_.w = BFL(P3,3); \
    *(float4*)&(BUF)[768 + 4 * lane] = f_; }
#define LDSREAD(H0, H1, H2, H3, BUF) {                                      \
    H0 = *(const float4*)&(BUF)[4 * lane];                                  \
    H1 = *(const float4*)&(BUF)[256 + 4 * lane];                            \
    H2 = *(const float4*)&(BUF)[512 + 4 * lane];                            \
    H3 = *(const float4*)&(BUF)[768 + 4 * lane]; }

// ---- register-resident weight row: 16 named scalars per 64 owned elems ----
#define ROW_DECL(P) float P##_0,P##_1,P##_2,P##_3,P##_4,P##_5,P##_6,P##_7,  \
                          P##_8,P##_9,P##_a,P##_b,P##_c,P##_d,P##_e,P##_f
#define ROW_LOAD(P, RP) {                                                   \
    float4 t0_ = *(const float4*)(RP);                                      \
    float4 t1_ = *(const float4*)((RP) + 256);                              \
    float4 t2_ = *(const float4*)((RP) + 512);                              \
    float4 t3_ = *(const float4*)((RP) + 768);                              \
    P##_0=t0_.x; P##_1=t0_.y; P##_2=t0_.z; P##_3=t0_.w;                     \
    P##_4=t1_.x; P##_5=t1_.y; P##_6=t1_.z; P##_7=t1_.w;                     \
    P##_8=t2_.x; P##_9=t2_.y; P##_a=t2_.z; P##_b=t2_.w;                     \
    P##_c=t3_.x; P##_d=t3_.y; P##_e=t3_.z; P##_f=t3_.w; }
#define ROW_PIN(P) asm volatile("" :                                        \
    "+v"(P##_0),"+v"(P##_1),"+v"(P##_2),"+v"(P##_3),                        \
    "+v"(P##_4),"+v"(P##_5),"+v"(P##_6),"+v"(P##_7),                        \
    "+v"(P##_8),"+v"(P##_9),"+v"(P##_a),"+v"(P##_b),                        \
    "+v"(P##_c),"+v"(P##_d),"+v"(P##_e),"+v"(P##_f))
#define ROW_DOTF(D, P, H0, H1, H2, H3) {                                    \
    D=__builtin_fmaf(P##_0,(H0).x,D); D=__builtin_fmaf(P##_1,(H0).y,D);     \
    D=__builtin_fmaf(P##_2,(H0).z,D); D=__builtin_fmaf(P##_3,(H0).w,D);     \
    D=__builtin_fmaf(P##_4,(H1).x,D); D=__builtin_fmaf(P##_5,(H1).y,D);     \
    D=__builtin_fmaf(P##_6,(H1).z,D); D=__builtin_fmaf(P##_7,(H1).w,D);     \
    D=__builtin_fmaf(P##_8,(H2).x,D); D=__builtin_fmaf(P##_9,(H2).y,D);     \
    D=__builtin_fmaf(P##_a,(H2).z,D); D=__builtin_fmaf(P##_b,(H2).w,D);     \
    D=__builtin_fmaf(P##_c,(H3).x,D); D=__builtin_fmaf(P##_d,(H3).y,D);     \
    D=__builtin_fmaf(P##_e,(H3).z,D); D=__builtin_fmaf(P##_f,(H3).w,D); }
#define ROW_DOTP(D, P, Q0, Q1, Q2, Q3) {                                    \
    D=__builtin_fmaf(P##_0,BFL(Q0,0),D); D=__builtin_fmaf(P##_1,BFL(Q0,1),D); \
    D=__builtin_fmaf(P##_2,BFL(Q0,2),D); D=__builtin_fmaf(P##_3,BFL(Q0,3),D); \
    D=__builtin_fmaf(P##_4,BFL(Q1,0),D); D=__builtin_fmaf(P##_5,BFL(Q1,1),D); \
    D=__builtin_fmaf(P##_6,BFL(Q1,2),D); D=__builtin_fmaf(P##_7,BFL(Q1,3),D); \
    D=__builtin_fmaf(P##_8,BFL(Q2,0),D); D=__builtin_fmaf(P##_9,BFL(Q2,1),D); \
    D=__builtin_fmaf(P##_a,BFL(Q2,2),D); D=__builtin_fmaf(P##_b,BFL(Q2,3),D); \
    D=__builtin_fmaf(P##_c,BFL(Q3,0),D); D=__builtin_fmaf(P##_d,BFL(Q3,1),D); \
    D=__builtin_fmaf(P##_e,BFL(Q3,2),D); D=__builtin_fmaf(P##_f,BFL(Q3,3),D); }

// ---------------- fused 2-layer pipelined LSTM recurrence ----------------
// 256 blocks x 512 threads (1 block/CU, 8 waves = 2 waves/EU). waves_per_eu
// FIXED at (2,2) so the register allocator budgets 256 VGPRs/wave and the
// pinned weight scalars stay register-resident (r6: min-only bound made RA
// target 4 waves/EU = 128 VGPRs and spill the L1 weights to scratch).
// Blocks 0..127: layer 0; 128..255: layer 1 (1 step behind via hist0).
// Wave wv owns unit j = bid*8+wv; lane l owns k = {4l..4l+3} + 256q.
// Stager wave(s) poll packed global vector (LLC-bypass dwordx4), stage f32
// to LDS conflict-free, publish LDS flag; consumers spin flag + ds_read_b128.
// No __syncthreads in the loop: distance-2 overwrite safety via the stagers'
// own global polls (tags include this block's own units; see r6 analysis).
__attribute__((amdgpu_waves_per_eu(2, 2)))
__global__ __launch_bounds__(512) void lstm_fused(
    const float* __restrict__ Whh0,           // [4H][H]
    const float* __restrict__ pre0,           // [T][4H] (x-proj + both biases)
    const float* __restrict__ Wih1,           // [4H][H]
    const float* __restrict__ Whh1,           // [4H][H]
    const float* __restrict__ bih1,           // [4H]
    const float* __restrict__ bhh1,           // [4H]
    unsigned* __restrict__ hist0,             // [T][H] packed h0 history
    unsigned* __restrict__ hist1,             // [T][H] packed h1 history
    unsigned short* __restrict__ y1b,         // [T][H] bf16 layer-1 output
    float* __restrict__ hfb,                  // out + T*V      (h stack [2][H])
    float* __restrict__ cfb) {                // out + T*V + 2H (c stack [2][H])
    const int wv   = threadIdx.x >> 6;
    const int lane = threadIdx.x & 63;

    __shared__ float hS[4][HH];               // [0/1]: A parity, [2/3]: B parity
    __shared__ int flagA, flagB;
    if (threadIdx.x == 0) { flagA = 0; flagB = 0; }
    __syncthreads();

    uint32x4 p0, p1, p2, p3, q0, q1, q2, q3;
    float4 h0_, h1_, h2_, h3_;

    if (blockIdx.x < 128) {
        // ================= layer 0 =================
        const int j = blockIdx.x * 8 + wv;
        ROW_DECL(wI); ROW_DECL(wF); ROW_DECL(wG); ROW_DECL(wO);
        ROW_LOAD(wI, Whh0 + (size_t)(0 * HH + j) * HH + 4 * lane);
        ROW_LOAD(wF, Whh0 + (size_t)(1 * HH + j) * HH + 4 * lane);
        ROW_LOAD(wG, Whh0 + (size_t)(2 * HH + j) * HH + 4 * lane);
        ROW_LOAD(wO, Whh0 + (size_t)(3 * HH + j) * HH + 4 * lane);
        ROW_PIN(wI); ROW_PIN(wF); ROW_PIN(wG); ROW_PIN(wO);

        float c = 0.f;
        float px0 = pre0[0 * HH + j], px1 = pre0[1 * HH + j];
        float px2 = pre0[2 * HH + j], px3 = pre0[3 * HH + j];

        for (int t = 0; t < TT; ++t) {
            float nx0 = 0.f, nx1 = 0.f, nx2 = 0.f, nx3 = 0.f;
            if (t + 1 < TT) {
                const float* pp = pre0 + (size_t)(t + 1) * 4 * HH + j;
                nx0 = pp[0]; nx1 = pp[HH]; nx2 = pp[2 * HH]; nx3 = pp[3 * HH];
            }
            const int par = t & 1;
            float d0 = 0.f, d1 = 0.f, d2 = 0.f, d3 = 0.f;
            if (wv == 0) {
                if (t > 0) {
                    const unsigned want = (unsigned)t;
                    POLL4(p0, p1, p2, p3, hist0 + (size_t)(t - 1) * HH, want);
                    STAGE(hS[par], p0, p1, p2, p3);
                }
                flag_set(&flagA, t + 1);
                if (t > 0) {
                    ROW_DOTP(d0, wI, p0, p1, p2, p3);
                    ROW_DOTP(d1, wF, p0, p1, p2, p3);
                    ROW_DOTP(d2, wG, p0, p1, p2, p3);
                    ROW_DOTP(d3, wO, p0, p1, p2, p3);
                }
            } else {
                flag_spin(&flagA, t + 1);
                if (t > 0) {
                    LDSREAD(h0_, h1_, h2_, h3_, hS[par]);
                    ROW_DOTF(d0, wI, h0_, h1_, h2_, h3_);
                    ROW_DOTF(d1, wF, h0_, h1_, h2_, h3_);
                    ROW_DOTF(d2, wG, h0_, h1_, h2_, h3_);
                    ROW_DOTF(d3, wO, h0_, h1_, h2_, h3_);
                }
            }
            if (t > 0) { RED(d0); RED(d1); RED(d2); RED(d3); }
            float i_ = sigm(px0 + d0), f_ = sigm(px1 + d1);
            float g_ = tanh_s(px2 + d2), o_ = sigm(px3 + d3);
            c = f_ * c + i_ * g_;
            float h = o_ * tanh_s(c);
            if (lane == 0) {
                unsigned pack = ((unsigned)(t + 1) << 16) | (unsigned)f2b(h);
                PUBLISH(hist0 + (size_t)t * HH + j, pack);
                if (t == TT - 1) { hfb[j] = h; cfb[j] = c; }
            }
            px0 = nx0; px1 = nx1; px2 = nx2; px3 = nx3;
        }
    } else {
        // ================= layer 1 (1 step behind) =================
        const int j = (blockIdx.x - 128) * 8 + wv;
        ROW_DECL(iI); ROW_DECL(iF); ROW_DECL(iG); ROW_DECL(iO);
        ROW_DECL(hI); ROW_DECL(hF); ROW_DECL(hG); ROW_DECL(hO);
        ROW_LOAD(iI, Wih1 + (size_t)(0 * HH + j) * HH + 4 * lane);
        ROW_LOAD(iF, Wih1 + (size_t)(1 * HH + j) * HH + 4 * lane);
        ROW_LOAD(iG, Wih1 + (size_t)(2 * HH + j) * HH + 4 * lane);
        ROW_LOAD(iO, Wih1 + (size_t)(3 * HH + j) * HH + 4 * lane);
        ROW_LOAD(hI, Whh1 + (size_t)(0 * HH + j) * HH + 4 * lane);
        ROW_LOAD(hF, Whh1 + (size_t)(1 * HH + j) * HH + 4 * lane);
        ROW_LOAD(hG, Whh1 + (size_t)(2 * HH + j) * HH + 4 * lane);
        ROW_LOAD(hO, Whh1 + (size_t)(3 * HH + j) * HH + 4 * lane);
        ROW_PIN(iI); ROW_PIN(iF); ROW_PIN(iG); ROW_PIN(iO);
        ROW_PIN(hI); ROW_PIN(hF); ROW_PIN(hG); ROW_PIN(hO);
        float bs0 = bih1[0 * HH + j] + bhh1[0 * HH + j];
        float bs1 = bih1[1 * HH + j] + bhh1[1 * HH + j];
        float bs2 = bih1[2 * HH + j] + bhh1[2 * HH + j];
        float bs3 = bih1[3 * HH + j] + bhh1[3 * HH + j];

        float c = 0.f;
        for (int t = 0; t < TT; ++t) {
            const int par = t & 1;
            float d0 = 0.f, d1 = 0.f, d2 = 0.f, d3 = 0.f;
            if (wv == 0) {
                // A-stager: h0_t (tag t+1)
                const unsigned want = (unsigned)(t + 1);
                POLL4(p0, p1, p2, p3, hist0 + (size_t)t * HH, want);
                STAGE(hS[par], p0, p1, p2, p3);
                flag_set(&flagA, t + 1);
                ROW_DOTP(d0, iI, p0, p1, p2, p3);
                ROW_DOTP(d1, iF, p0, p1, p2, p3);
                ROW_DOTP(d2, iG, p0, p1, p2, p3);
                ROW_DOTP(d3, iO, p0, p1, p2, p3);
                flag_spin(&flagB, t + 1);
                if (t > 0) {
                    LDSREAD(h0_, h1_, h2_, h3_, hS[2 + par]);
                    ROW_DOTF(d0, hI, h0_, h1_, h2_, h3_);
                    ROW_DOTF(d1, hF, h0_, h1_, h2_, h3_);
                    ROW_DOTF(d2, hG, h0_, h1_, h2_, h3_);
                    ROW_DOTF(d3, hO, h0_, h1_, h2_, h3_);
                }
            } else if (wv == 1) {
                // B-stager: h1_{t-1} (tag t)
                if (t > 0) {
                    const unsigned want = (unsigned)t;
                    POLL4(q0, q1, q2, q3, hist1 + (size_t)(t - 1) * HH, want);
                    STAGE(hS[2 + par], q0, q1, q2, q3);
                }
                flag_set(&flagB, t + 1);
                flag_spin(&flagA, t + 1);
                LDSREAD(h0_, h1_, h2_, h3_, hS[par]);
                ROW_DOTF(d0, iI, h0_, h1_, h2_, h3_);
                ROW_DOTF(d1, iF, h0_, h1_, h2_, h3_);
                ROW_DOTF(d2, iG, h0_, h1_, h2_, h3_);
                ROW_DOTF(d3, iO, h0_, h1_, h2_, h3_);
                if (t > 0) {
                    ROW_DOTP(d0, hI, q0, q1, q2, q3);
                    ROW_DOTP(d1, hF, q0, q1, q2, q3);
                    ROW_DOTP(d2, hG, q0, q1, q2, q3);
                    ROW_DOTP(d3, hO, q0, q1, q2, q3);
                }
            } else {
                flag_spin(&flagA, t + 1);
                LDSREAD(h0_, h1_, h2_, h3_, hS[par]);
                ROW_DOTF(d0, iI, h0_, h1_, h2_, h3_);
                ROW_DOTF(d1, iF, h0_, h1_, h2_, h3_);
                ROW_DOTF(d2, iG, h0_, h1_, h2_, h3_);
                ROW_DOTF(d3, iO, h0_, h1_, h2_, h3_);
                flag_spin(&flagB, t + 1);
                if (t > 0) {
                    LDSREAD(h0_, h1_, h2_, h3_, hS[2 + par]);
                    ROW_DOTF(d0, hI, h0_, h1_, h2_, h3_);
                    ROW_DOTF(d1, hF, h0_, h1_, h2_, h3_);
                    ROW_DOTF(d2, hG, h0_, h1_, h2_, h3_);
                    ROW_DOTF(d3, hO, h0_, h1_, h2_, h3_);
                }
            }
            RED(d0); RED(d1); RED(d2); RED(d3);
            float i_ = sigm(bs0 + d0), f_ = sigm(bs1 + d1);
            float g_ = tanh_s(bs2 + d2), o_ = sigm(bs3 + d3);
            c = f_ * c + i_ * g_;
            float h = o_ * tanh_s(c);
            if (lane == 0) {
                unsigned short hb16 = f2b(h);
                unsigned pack = ((unsigned)(t + 1) << 16) | (unsigned)hb16;
                PUBLISH(hist1 + (size_t)t * HH + j, pack);
                y1b[(size_t)t * HH + j] = hb16;
                if (t == TT - 1) { hfb[HH + j] = h; cfb[HH + j] = c; }
            }
        }
    }
}

// ---------------- row softmax over V=32000, in place ----------------
__global__ __launch_bounds__(256) void softmax_kernel(float* __restrict__ data) {
    const int row = blockIdx.x;
    const int tid = threadIdx.x;
    float* p = data + (size_t)row * VV;
    float m = -1e30f, s = 0.f;
    for (int i = tid * 4; i < VV; i += 1024) {
        float4 v = *(const float4*)(p + i);
        float x[4] = {v.x, v.y, v.z, v.w};
#pragma unroll
        for (int q = 0; q < 4; ++q) {
            float xv = x[q];
            if (xv > m) { s = s * __expf(m - xv) + 1.f; m = xv; }
            else s += __expf(xv - m);
        }
    }
#pragma unroll
    for (int off = 32; off; off >>= 1) {
        float mo = __shfl_xor(m, off);
        float so = __shfl_xor(s, off);
        float mn = fmaxf(m, mo);
        s = s * __expf(m - mn) + so * __expf(mo - mn);
        m = mn;
    }
    __shared__ float sm[4], ss[4];
    int wvv = tid >> 6;
    if ((tid & 63) == 0) { sm[wvv] = m; ss[wvv] = s; }
    __syncthreads();
    float M = fmaxf(fmaxf(sm[0], sm[1]), fmaxf(sm[2], sm[3]));
    float S = ss[0] * __expf(sm[0] - M) + ss[1] * __expf(sm[1] - M) +
              ss[2] * __expf(sm[2] - M) + ss[3] * __expf(sm[3] - M);
    float inv = 1.f / S;
    for (int i = tid * 4; i < VV; i += 1024) {
        float4 v = *(const float4*)(p + i);
        v.x = __expf(v.x - M) * inv;
        v.y = __expf(v.y - M) * inv;
        v.z = __expf(v.z - M) * inv;
        v.w = __expf(v.w - M) * inv;
        *(float4*)(p + i) = v;
    }
}

extern "C" void kernel_launch(void* const* d_in, const int* in_sizes, int n_in,
                              void* d_out, int out_size, void* d_ws, size_t ws_size,
                              hipStream_t stream) {
    const int*   inputs = (const int*)d_in[0];
    const float* emb    = (const float*)d_in[1];
    const float* w_ih0  = (const float*)d_in[2];
    const float* w_hh0  = (const float*)d_in[3];
    const float* b_ih0  = (const float*)d_in[4];
    const float* b_hh0  = (const float*)d_in[5];
    const float* w_ih1  = (const float*)d_in[6];
    const float* w_hh1  = (const float*)d_in[7];
    const float* b_ih1  = (const float*)d_in[8];
    const float* b_hh1  = (const float*)d_in[9];
    const float* w_out  = (const float*)d_in[10];
    const float* b_out  = (const float*)d_in[11];
    float* out = (float*)d_out;

    char* ws = (char*)d_ws;
    size_t off = 0;
    auto alloc = [&](size_t bytes) -> void* {
        void* p = ws + off;
        off += (bytes + 255) & ~(size_t)255;
        return p;
    };
    float* pre0          = (float*)alloc((size_t)TT * 4 * HH * 4);
    unsigned short* xsb  = (unsigned short*)alloc((size_t)TT * EE * 2);
    unsigned short* w0b  = (unsigned short*)alloc((size_t)4 * HH * EE * 2);
    unsigned short* wob  = (unsigned short*)alloc((size_t)VV * HH * 2);
    unsigned short* y1b  = (unsigned short*)alloc((size_t)TT * HH * 2);
    unsigned* hist0      = (unsigned*)alloc((size_t)TT * HH * 4);
    unsigned* hist1      = (unsigned*)alloc((size_t)TT * HH * 4);
    if (off > ws_size) return;

    (void)hipMemsetAsync(hist0, 0, (size_t)TT * HH * 4, stream);
    (void)hipMemsetAsync(hist1, 0, (size_t)TT * HH * 4, stream);

    embed_kernel<<<TT, 128, 0, stream>>>(inputs, emb, xsb);
    f32_to_bf16<<<1024, 256, 0, stream>>>(w_ih0, w0b, (long)4 * HH * EE / 4);
    f32_to_bf16<<<2048, 256, 0, stream>>>(w_out, wob, (long)VV * HH / 4);

    // pre0 = xs @ w_ih0^T + b_ih0 + b_hh0
    gemm_bf16_nt<<<dim3(4 * HH / 128, TT / 128), 256, 0, stream>>>(
        xsb, w0b, b_ih0, b_hh0, pre0, EE, 4 * HH);

    // fused pipelined 2-layer recurrence
    lstm_fused<<<256, 512, 0, stream>>>(
        w_hh0, pre0, w_ih1, w_hh1, b_ih1, b_hh1,
        hist0, hist1, y1b,
        out + (size_t)TT * VV, out + (size_t)TT * VV + 2 * HH);

    // logits = ys1 @ w_out^T + b_out  (into d_out, softmax in place after)
    gemm_bf16_nt<<<dim3(VV / 128, TT / 128), 256, 0, stream>>>(
        y1b, wob, b_out, nullptr, out, HH, VV);
    softmax_kernel<<<TT, 256, 0, stream>>>(out);
}

// Round 8
// 9659.789 us; speedup vs baseline: 1.0598x; 1.0037x over previous
//
#include <hip/hip_runtime.h>
#include <hip/hip_fp16.h>
#include <cstdint>
#include <cstddef>

#define TT 2048
#define VV 32000
#define EE 512
#define HH 1024

typedef __bf16 bf16x8 __attribute__((ext_vector_type(8)));
typedef float f32x4 __attribute__((ext_vector_type(4)));
typedef unsigned uint32x4 __attribute__((ext_vector_type(4)));

static __device__ __forceinline__ unsigned short f2b(float f) {
    unsigned u = __float_as_uint(f);
    unsigned r = (u + 0x7fffu + ((u >> 16) & 1u)) >> 16;   // RNE
    return (unsigned short)r;
}
static __device__ __forceinline__ float sigm(float x) {
    return __builtin_amdgcn_rcpf(1.f + __expf(-x));
}
static __device__ __forceinline__ float tanh_s(float x) {
    float a = fabsf(x);
    float e = __expf(-2.f * a);
    float r = (1.f - e) * __builtin_amdgcn_rcpf(1.f + e);
    return copysignf(r, x);
}
static __device__ __forceinline__ void flag_set(int* f, int v) {
    __hip_atomic_store(f, v, __ATOMIC_RELEASE, __HIP_MEMORY_SCOPE_WORKGROUP);
}
static __device__ __forceinline__ void flag_spin(int* f, int want) {
    while (__hip_atomic_load(f, __ATOMIC_ACQUIRE, __HIP_MEMORY_SCOPE_WORKGROUP) < want) {}
}
// f16-pair pack/unpack for register-resident weights
static __device__ __forceinline__ unsigned pkf(float lo, float hi) {
    return ((unsigned)__half_as_ushort(__float2half(hi)) << 16) |
           (unsigned)__half_as_ushort(__float2half(lo));
}
static __device__ __forceinline__ float pklo(unsigned u) {
    return __half2float(__ushort_as_half((unsigned short)(u & 0xffffu)));
}
static __device__ __forceinline__ float pkhi(unsigned u) {
    return __half2float(__ushort_as_half((unsigned short)(u >> 16)));
}

// ---------------- embedding gather -> bf16 ----------------
__global__ __launch_bounds__(128) void embed_kernel(
    const int* __restrict__ tok, const float* __restrict__ emb,
    unsigned short* __restrict__ xs_b) {
    int t = blockIdx.x;
    int e4 = threadIdx.x;
    const float4* src = (const float4*)(emb + (size_t)tok[t] * EE);
    float4 v = src[e4];
    ushort4 o;
    o.x = f2b(v.x); o.y = f2b(v.y); o.z = f2b(v.z); o.w = f2b(v.w);
    ((ushort4*)(xs_b + (size_t)t * EE))[e4] = o;
}

// ---------------- generic f32 -> bf16 ----------------
__global__ __launch_bounds__(256) void f32_to_bf16(
    const float* __restrict__ in, unsigned short* __restrict__ out, long n4) {
    long i = (long)blockIdx.x * blockDim.x + threadIdx.x;
    long stride = (long)gridDim.x * blockDim.x;
    for (; i < n4; i += stride) {
        float4 v = ((const float4*)in)[i];
        ushort4 o;
        o.x = f2b(v.x); o.y = f2b(v.y); o.z = f2b(v.z); o.w = f2b(v.w);
        ((ushort4*)out)[i] = o;
    }
}

// ---------------- bf16 MFMA GEMM: C[M,N] = A[M,K] * B[N,K]^T + bias ----------------
__global__ __launch_bounds__(256) void gemm_bf16_nt(
    const unsigned short* __restrict__ A,   // [M][K] bf16 bits
    const unsigned short* __restrict__ B,   // [N][K] bf16 bits
    const float* __restrict__ bias1,        // [N] or null
    const float* __restrict__ bias2,        // [N] or null
    float* __restrict__ C,                  // [M][N]
    int K, int N) {
    __shared__ unsigned short ldsA[128 * 64];
    __shared__ unsigned short ldsB[128 * 64];
    const int tid = threadIdx.x;
    const int l = tid & 63;
    const int w = tid >> 6;
    const int wm = (w >> 1) * 64;
    const int wn = (w & 1) * 64;
    const int bm = blockIdx.y, bn = blockIdx.x;
    const size_t a_base = (size_t)bm * 128 * K;
    const size_t b_base = (size_t)bn * 128 * K;
    const int srow = tid >> 3;
    const int skc = tid & 7;

    f32x4 acc[4][4];
    for (int i = 0; i < 4; ++i)
        for (int j = 0; j < 4; ++j)
            acc[i][j] = (f32x4){0.f, 0.f, 0.f, 0.f};

    for (int kt = 0; kt < K; kt += 64) {
        uint4 av[4], bv[4];
#pragma unroll
        for (int i = 0; i < 4; ++i) {
            int row = srow + i * 32;
            av[i] = ((const uint4*)(A + a_base + (size_t)row * K + kt))[skc];
            bv[i] = ((const uint4*)(B + b_base + (size_t)row * K + kt))[skc];
        }
        __syncthreads();
#pragma unroll
        for (int i = 0; i < 4; ++i) {
            int row = srow + i * 32;
            int off = row * 128 + ((skc * 16) ^ ((row & 7) << 4));
            *(uint4*)((char*)ldsA + off) = av[i];
            *(uint4*)((char*)ldsB + off) = bv[i];
        }
        __syncthreads();
#pragma unroll
        for (int ks = 0; ks < 2; ++ks) {
            bf16x8 af[4], bfr[4];
            int kb = ks * 64 + (l >> 4) * 16;
#pragma unroll
            for (int f = 0; f < 4; ++f) {
                int ar = wm + f * 16 + (l & 15);
                af[f] = *(const bf16x8*)((const char*)ldsA + ar * 128 + (kb ^ ((ar & 7) << 4)));
                int br = wn + f * 16 + (l & 15);
                bfr[f] = *(const bf16x8*)((const char*)ldsB + br * 128 + (kb ^ ((br & 7) << 4)));
            }
#pragma unroll
            for (int fm = 0; fm < 4; ++fm)
#pragma unroll
                for (int fn = 0; fn < 4; ++fn)
                    acc[fm][fn] = __builtin_amdgcn_mfma_f32_16x16x32_bf16(
                        af[fm], bfr[fn], acc[fm][fn], 0, 0, 0);
        }
    }
    const int r0 = (l >> 4) * 4, cn = (l & 15);
#pragma unroll
    for (int fm = 0; fm < 4; ++fm)
#pragma unroll
        for (int fn = 0; fn < 4; ++fn) {
            int col = bn * 128 + wn + fn * 16 + cn;
            float bb = (bias1 ? bias1[col] : 0.f) + (bias2 ? bias2[col] : 0.f);
#pragma unroll
            for (int r = 0; r < 4; ++r) {
                int rowg = bm * 128 + wm + fm * 16 + r0 + r;
                C[(size_t)rowg * N + col] = acc[fm][fn][r] + bb;
            }
        }
}

// ======== macros for the recurrence kernel ========
// packed comm word: {tag16 (hi) | bf16 h bits (lo)}
#define BFL(P, E) __uint_as_float((P)[E] << 16)
#define CHK4(P, W) ((((P)[0] >> 16) == (W)) & (((P)[1] >> 16) == (W)) & \
                    (((P)[2] >> 16) == (W)) & (((P)[3] >> 16) == (W)))
// 4x dwordx4 LLC-bypass poll; lane covers elements {4l, 256+4l, 512+4l, 768+4l}..+3
#define POLL4(P0, P1, P2, P3, BASE, WANT)                                   \
    for (;;) {                                                              \
        asm volatile(                                                       \
            "global_load_dwordx4 %0, %4, off sc0 sc1\n\t"                   \
            "global_load_dwordx4 %1, %5, off sc0 sc1\n\t"                   \
            "global_load_dwordx4 %2, %6, off sc0 sc1\n\t"                   \
            "global_load_dwordx4 %3, %7, off sc0 sc1\n\t"                   \
            "s_waitcnt vmcnt(0)"                                            \
            : "=&v"(P0), "=&v"(P1), "=&v"(P2), "=&v"(P3)                    \
            : "v"((BASE) + 4 * lane), "v"((BASE) + 4 * lane + 256),         \
              "v"((BASE) + 4 * lane + 512), "v"((BASE) + 4 * lane + 768)    \
            : "memory");                                                    \
        if (CHK4(P0, WANT) & CHK4(P1, WANT) & CHK4(P2, WANT) & CHK4(P3, WANT)) break; \
        __builtin_amdgcn_s_sleep(1);                                        \
    }
#define PUBLISH(PTR, PK)                                                    \
    asm volatile("global_store_dword %0, %1, off sc0 sc1"                   \
                 :: "v"(PTR), "v"(PK) : "memory")
#define RED(D) { D += __shfl_xor(D, 32); D += __shfl_xor(D, 16);            \
                 D += __shfl_xor(D, 8);  D += __shfl_xor(D, 4);             \
                 D += __shfl_xor(D, 2);  D += __shfl_xor(D, 1); }
#define STAGE(BUF, P0, P1, P2, P3) {                                        \
    float4 f_;                                                              \
    f_.x = BFL(P0,0); f_.y = BFL(P0,1); f_.z = BFL(P0,2); f_.w = BFL(P0,3); \
    *(float4*)&(BUF)[4 * lane] = f_;                                        \
    f_.x = BFL(P1,0); f_.y = BFL(P1,1); f_.z = BFL(P1,2); f_.w = BFL(P1,3); \
    *(float4*)&(BUF)[256 + 4 * lane] = f_;                                  \
    f_.x = BFL(P2,0); f_.y = BFL(P2,1); f_.z = BFL(P2,2); f_.w = BFL(P2,3); \
    *(float4*)&(BUF)[512 + 4 * lane] = f_;                                  \
    f_.x = BFL(P3,0); f_.y = BFL(P3,1); f_.z = BFL(P3,2); f_.w = BFL(P3,3); \
    *(float4*)&(BUF)[768 + 4 * lane] = f_; }
#define LDSREAD(H0, H1, H2, H3, BUF) {                                      \
    H0 = *(const float4*)&(BUF)[4 * lane];                                  \
    H1 = *(const float4*)&(BUF)[256 + 4 * lane];                            \
    H2 = *(const float4*)&(BUF)[512 + 4 * lane];                            \
    H3 = *(const float4*)&(BUF)[768 + 4 * lane]; }

// ---- register-resident weight row: 8 packed-f16-pair u32 per 64 owned elems ----
#define PK_DECL(P) unsigned P##_0,P##_1,P##_2,P##_3,P##_4,P##_5,P##_6,P##_7
#define PK_LOAD(P, RP) {                                                    \
    float4 t0_ = *(const float4*)(RP);                                      \
    float4 t1_ = *(const float4*)((RP) + 256);                              \
    float4 t2_ = *(const float4*)((RP) + 512);                              \
    float4 t3_ = *(const float4*)((RP) + 768);                              \
    P##_0 = pkf(t0_.x, t0_.y); P##_1 = pkf(t0_.z, t0_.w);                   \
    P##_2 = pkf(t1_.x, t1_.y); P##_3 = pkf(t1_.z, t1_.w);                   \
    P##_4 = pkf(t2_.x, t2_.y); P##_5 = pkf(t2_.z, t2_.w);                   \
    P##_6 = pkf(t3_.x, t3_.y); P##_7 = pkf(t3_.z, t3_.w); }
#define PK_PIN(P) asm volatile("" :                                         \
    "+v"(P##_0),"+v"(P##_1),"+v"(P##_2),"+v"(P##_3),                        \
    "+v"(P##_4),"+v"(P##_5),"+v"(P##_6),"+v"(P##_7))
#define PK_DOT(D, P, H0, H1, H2, H3) {                                      \
    D=__builtin_fmaf(pklo(P##_0),(H0).x,D); D=__builtin_fmaf(pkhi(P##_0),(H0).y,D); \
    D=__builtin_fmaf(pklo(P##_1),(H0).z,D); D=__builtin_fmaf(pkhi(P##_1),(H0).w,D); \
    D=__builtin_fmaf(pklo(P##_2),(H1).x,D); D=__builtin_fmaf(pkhi(P##_2),(H1).y,D); \
    D=__builtin_fmaf(pklo(P##_3),(H1).z,D); D=__builtin_fmaf(pkhi(P##_3),(H1).w,D); \
    D=__builtin_fmaf(pklo(P##_4),(H2).x,D); D=__builtin_fmaf(pkhi(P##_4),(H2).y,D); \
    D=__builtin_fmaf(pklo(P##_5),(H2).z,D); D=__builtin_fmaf(pkhi(P##_5),(H2).w,D); \
    D=__builtin_fmaf(pklo(P##_6),(H3).x,D); D=__builtin_fmaf(pkhi(P##_6),(H3).y,D); \
    D=__builtin_fmaf(pklo(P##_7),(H3).z,D); D=__builtin_fmaf(pkhi(P##_7),(H3).w,D); }

// ---------------- fused 2-layer pipelined LSTM recurrence ----------------
// 256 blocks x 512 threads (1 block/CU). Blocks 0..127: layer 0; 128..255:
// layer 1 (1 step behind via hist0). Wave wv owns unit j = bid*8+wv; lane l
// owns elements {4l..4l+3}+256q. Weights live in packed-f16-pair u32 VGPRs
// (L0: 32 regs, L1: 64 regs) so peak pressure fits the RA's ~128 budget —
// r6/r7 showed pinned fp32 arrays (128 regs) get spilled to scratch at
// VGPR_Count=104 no matter the waves_per_eu hint. All waves read staged h
// from LDS (stager included). No __syncthreads in the loop; distance-2
// overwrite safety via the stagers' own global polls (r7 analysis).
__attribute__((amdgpu_waves_per_eu(2, 2)))
__global__ __launch_bounds__(512) void lstm_fused(
    const float* __restrict__ Whh0,           // [4H][H]
    const float* __restrict__ pre0,           // [T][4H] (x-proj + both biases)
    const float* __restrict__ Wih1,           // [4H][H]
    const float* __restrict__ Whh1,           // [4H][H]
    const float* __restrict__ bih1,           // [4H]
    const float* __restrict__ bhh1,           // [4H]
    unsigned* __restrict__ hist0,             // [T][H] packed h0 history
    unsigned* __restrict__ hist1,             // [T][H] packed h1 history
    unsigned short* __restrict__ y1b,         // [T][H] bf16 layer-1 output
    float* __restrict__ hfb,                  // out + T*V      (h stack [2][H])
    float* __restrict__ cfb) {                // out + T*V + 2H (c stack [2][H])
    const int wv   = threadIdx.x >> 6;
    const int lane = threadIdx.x & 63;

    __shared__ float hS[4][HH];               // [0/1]: A parity, [2/3]: B parity
    __shared__ int flagA, flagB;
    if (threadIdx.x == 0) { flagA = 0; flagB = 0; }
    __syncthreads();

    uint32x4 p0, p1, p2, p3;
    float4 h0_, h1_, h2_, h3_;

    if (blockIdx.x < 128) {
        // ================= layer 0 =================
        const int j = blockIdx.x * 8 + wv;
        PK_DECL(wI); PK_DECL(wF); PK_DECL(wG); PK_DECL(wO);
        PK_LOAD(wI, Whh0 + (size_t)(0 * HH + j) * HH + 4 * lane);
        PK_LOAD(wF, Whh0 + (size_t)(1 * HH + j) * HH + 4 * lane);
        PK_LOAD(wG, Whh0 + (size_t)(2 * HH + j) * HH + 4 * lane);
        PK_LOAD(wO, Whh0 + (size_t)(3 * HH + j) * HH + 4 * lane);
        PK_PIN(wI); PK_PIN(wF); PK_PIN(wG); PK_PIN(wO);

        float c = 0.f;
        float px0 = pre0[0 * HH + j], px1 = pre0[1 * HH + j];
        float px2 = pre0[2 * HH + j], px3 = pre0[3 * HH + j];

        for (int t = 0; t < TT; ++t) {
            float nx0 = 0.f, nx1 = 0.f, nx2 = 0.f, nx3 = 0.f;
            if (t + 1 < TT) {
                const float* pp = pre0 + (size_t)(t + 1) * 4 * HH + j;
                nx0 = pp[0]; nx1 = pp[HH]; nx2 = pp[2 * HH]; nx3 = pp[3 * HH];
            }
            const int par = t & 1;
            if (wv == 0) {
                if (t > 0) {
                    const unsigned want = (unsigned)t;
                    POLL4(p0, p1, p2, p3, hist0 + (size_t)(t - 1) * HH, want);
                    STAGE(hS[par], p0, p1, p2, p3);
                }
                flag_set(&flagA, t + 1);
            } else {
                flag_spin(&flagA, t + 1);
            }
            float d0 = 0.f, d1 = 0.f, d2 = 0.f, d3 = 0.f;
            if (t > 0) {
                LDSREAD(h0_, h1_, h2_, h3_, hS[par]);
                PK_DOT(d0, wI, h0_, h1_, h2_, h3_);
                PK_DOT(d1, wF, h0_, h1_, h2_, h3_);
                PK_DOT(d2, wG, h0_, h1_, h2_, h3_);
                PK_DOT(d3, wO, h0_, h1_, h2_, h3_);
                RED(d0); RED(d1); RED(d2); RED(d3);
            }
            float i_ = sigm(px0 + d0), f_ = sigm(px1 + d1);
            float g_ = tanh_s(px2 + d2), o_ = sigm(px3 + d3);
            c = f_ * c + i_ * g_;
            float h = o_ * tanh_s(c);
            if (lane == 0) {
                unsigned pack = ((unsigned)(t + 1) << 16) | (unsigned)f2b(h);
                PUBLISH(hist0 + (size_t)t * HH + j, pack);
                if (t == TT - 1) { hfb[j] = h; cfb[j] = c; }
            }
            px0 = nx0; px1 = nx1; px2 = nx2; px3 = nx3;
        }
    } else {
        // ================= layer 1 (1 step behind) =================
        const int j = (blockIdx.x - 128) * 8 + wv;
        PK_DECL(iI); PK_DECL(iF); PK_DECL(iG); PK_DECL(iO);
        PK_DECL(hI); PK_DECL(hF); PK_DECL(hG); PK_DECL(hO);
        PK_LOAD(iI, Wih1 + (size_t)(0 * HH + j) * HH + 4 * lane);
        PK_LOAD(iF, Wih1 + (size_t)(1 * HH + j) * HH + 4 * lane);
        PK_LOAD(iG, Wih1 + (size_t)(2 * HH + j) * HH + 4 * lane);
        PK_LOAD(iO, Wih1 + (size_t)(3 * HH + j) * HH + 4 * lane);
        PK_LOAD(hI, Whh1 + (size_t)(0 * HH + j) * HH + 4 * lane);
        PK_LOAD(hF, Whh1 + (size_t)(1 * HH + j) * HH + 4 * lane);
        PK_LOAD(hG, Whh1 + (size_t)(2 * HH + j) * HH + 4 * lane);
        PK_LOAD(hO, Whh1 + (size_t)(3 * HH + j) * HH + 4 * lane);
        PK_PIN(iI); PK_PIN(iF); PK_PIN(iG); PK_PIN(iO);
        PK_PIN(hI); PK_PIN(hF); PK_PIN(hG); PK_PIN(hO);
        float bs0 = bih1[0 * HH + j] + bhh1[0 * HH + j];
        float bs1 = bih1[1 * HH + j] + bhh1[1 * HH + j];
        float bs2 = bih1[2 * HH + j] + bhh1[2 * HH + j];
        float bs3 = bih1[3 * HH + j] + bhh1[3 * HH + j];

        float c = 0.f;
        for (int t = 0; t < TT; ++t) {
            const int par = t & 1;
            if (wv == 0) {
                // A-stager: h0_t (tag t+1)
                const unsigned want = (unsigned)(t + 1);
                POLL4(p0, p1, p2, p3, hist0 + (size_t)t * HH, want);
                STAGE(hS[par], p0, p1, p2, p3);
                flag_set(&flagA, t + 1);
            } else if (wv == 1) {
                // B-stager: h1_{t-1} (tag t)
                if (t > 0) {
                    const unsigned want = (unsigned)t;
                    POLL4(p0, p1, p2, p3, hist1 + (size_t)(t - 1) * HH, want);
                    STAGE(hS[2 + par], p0, p1, p2, p3);
                }
                flag_set(&flagB, t + 1);
            }
            if (wv != 0) flag_spin(&flagA, t + 1);
            float d0 = 0.f, d1 = 0.f, d2 = 0.f, d3 = 0.f;
            LDSREAD(h0_, h1_, h2_, h3_, hS[par]);
            PK_DOT(d0, iI, h0_, h1_, h2_, h3_);
            PK_DOT(d1, iF, h0_, h1_, h2_, h3_);
            PK_DOT(d2, iG, h0_, h1_, h2_, h3_);
            PK_DOT(d3, iO, h0_, h1_, h2_, h3_);
            if (wv != 1) flag_spin(&flagB, t + 1);
            if (t > 0) {
                LDSREAD(h0_, h1_, h2_, h3_, hS[2 + par]);
                PK_DOT(d0, hI, h0_, h1_, h2_, h3_);
                PK_DOT(d1, hF, h0_, h1_, h2_, h3_);
                PK_DOT(d2, hG, h0_, h1_, h2_, h3_);
                PK_DOT(d3, hO, h0_, h1_, h2_, h3_);
            }
            RED(d0); RED(d1); RED(d2); RED(d3);
            float i_ = sigm(bs0 + d0), f_ = sigm(bs1 + d1);
            float g_ = tanh_s(bs2 + d2), o_ = sigm(bs3 + d3);
            c = f_ * c + i_ * g_;
            float h = o_ * tanh_s(c);
            if (lane == 0) {
                unsigned short hb16 = f2b(h);
                unsigned pack = ((unsigned)(t + 1) << 16) | (unsigned)hb16;
                PUBLISH(hist1 + (size_t)t * HH + j, pack);
                y1b[(size_t)t * HH + j] = hb16;
                if (t == TT - 1) { hfb[HH + j] = h; cfb[HH + j] = c; }
            }
        }
    }
}

// ---------------- row softmax over V=32000, in place ----------------
__global__ __launch_bounds__(256) void softmax_kernel(float* __restrict__ data) {
    const int row = blockIdx.x;
    const int tid = threadIdx.x;
    float* p = data + (size_t)row * VV;
    float m = -1e30f, s = 0.f;
    for (int i = tid * 4; i < VV; i += 1024) {
        float4 v = *(const float4*)(p + i);
        float x[4] = {v.x, v.y, v.z, v.w};
#pragma unroll
        for (int q = 0; q < 4; ++q) {
            float xv = x[q];
            if (xv > m) { s = s * __expf(m - xv) + 1.f; m = xv; }
            else s += __expf(xv - m);
        }
    }
#pragma unroll
    for (int off = 32; off; off >>= 1) {
        float mo = __shfl_xor(m, off);
        float so = __shfl_xor(s, off);
        float mn = fmaxf(m, mo);
        s = s * __expf(m - mn) + so * __expf(mo - mn);
        m = mn;
    }
    __shared__ float sm[4], ss[4];
    int wvv = tid >> 6;
    if ((tid & 63) == 0) { sm[wvv] = m; ss[wvv] = s; }
    __syncthreads();
    float M = fmaxf(fmaxf(sm[0], sm[1]), fmaxf(sm[2], sm[3]));
    float S = ss[0] * __expf(sm[0] - M) + ss[1] * __expf(sm[1] - M) +
              ss[2] * __expf(sm[2] - M) + ss[3] * __expf(sm[3] - M);
    float inv = 1.f / S;
    for (int i = tid * 4; i < VV; i += 1024) {
        float4 v = *(const float4*)(p + i);
        v.x = __expf(v.x - M) * inv;
        v.y = __expf(v.y - M) * inv;
        v.z = __expf(v.z - M) * inv;
        v.w = __expf(v.w - M) * inv;
        *(float4*)(p + i) = v;
    }
}

extern "C" void kernel_launch(void* const* d_in, const int* in_sizes, int n_in,
                              void* d_out, int out_size, void* d_ws, size_t ws_size,
                              hipStream_t stream) {
    const int*   inputs = (const int*)d_in[0];
    const float* emb    = (const float*)d_in[1];
    const float* w_ih0  = (const float*)d_in[2];
    const float* w_hh0  = (const float*)d_in[3];
    const float* b_ih0  = (const float*)d_in[4];
    const float* b_hh0  = (const float*)d_in[5];
    const float* w_ih1  = (const float*)d_in[6];
    const float* w_hh1  = (const float*)d_in[7];
    const float* b_ih1  = (const float*)d_in[8];
    const float* b_hh1  = (const float*)d_in[9];
    const float* w_out  = (const float*)d_in[10];
    const float* b_out  = (const float*)d_in[11];
    float* out = (float*)d_out;

    char* ws = (char*)d_ws;
    size_t off = 0;
    auto alloc = [&](size_t bytes) -> void* {
        void* p = ws + off;
        off += (bytes + 255) & ~(size_t)255;
        return p;
    };
    float* pre0          = (float*)alloc((size_t)TT * 4 * HH * 4);
    unsigned short* xsb  = (unsigned short*)alloc((size_t)TT * EE * 2);
    unsigned short* w0b  = (unsigned short*)alloc((size_t)4 * HH * EE * 2);
    unsigned short* wob  = (unsigned short*)alloc((size_t)VV * HH * 2);
    unsigned short* y1b  = (unsigned short*)alloc((size_t)TT * HH * 2);
    unsigned* hist0      = (unsigned*)alloc((size_t)TT * HH * 4);
    unsigned* hist1      = (unsigned*)alloc((size_t)TT * HH * 4);
    if (off > ws_size) return;

    (void)hipMemsetAsync(hist0, 0, (size_t)TT * HH * 4, stream);
    (void)hipMemsetAsync(hist1, 0, (size_t)TT * HH * 4, stream);

    embed_kernel<<<TT, 128, 0, stream>>>(inputs, emb, xsb);
    f32_to_bf16<<<1024, 256, 0, stream>>>(w_ih0, w0b, (long)4 * HH * EE / 4);
    f32_to_bf16<<<2048, 256, 0, stream>>>(w_out, wob, (long)VV * HH / 4);

    // pre0 = xs @ w_ih0^T + b_ih0 + b_hh0
    gemm_bf16_nt<<<dim3(4 * HH / 128, TT / 128), 256, 0, stream>>>(
        xsb, w0b, b_ih0, b_hh0, pre0, EE, 4 * HH);

    // fused pipelined 2-layer recurrence
    lstm_fused<<<256, 512, 0, stream>>>(
        w_hh0, pre0, w_ih1, w_hh1, b_ih1, b_hh1,
        hist0, hist1, y1b,
        out + (size_t)TT * VV, out + (size_t)TT * VV + 2 * HH);

    // logits = ys1 @ w_out^T + b_out  (into d_out, softmax in place after)
    gemm_bf16_nt<<<dim3(VV / 128, TT / 128), 256, 0, stream>>>(
        y1b, wob, b_out, nullptr, out, HH, VV);
    softmax_kernel<<<TT, 256, 0, stream>>>(out);
}

// Round 10
// 9646.855 us; speedup vs baseline: 1.0612x; 1.0013x over previous
//
#include <hip/hip_runtime.h>
#include <hip/hip_fp16.h>
#include <cstdint>
#include <cstddef>

#define TT 2048
#define VV 32000
#define EE 512
#define HH 1024
#define HSLOT 64         // ring slots (256 KB/layer, LLC-hot)
#define HMSK  (HSLOT - 1)

typedef __bf16 bf16x8 __attribute__((ext_vector_type(8)));
typedef float f32x4 __attribute__((ext_vector_type(4)));

static __device__ __forceinline__ unsigned short f2b(float f) {
    unsigned u = __float_as_uint(f);
    unsigned r = (u + 0x7fffu + ((u >> 16) & 1u)) >> 16;   // RNE
    return (unsigned short)r;
}
static __device__ __forceinline__ float sigm(float x) {
    return __builtin_amdgcn_rcpf(1.f + __expf(-x));
}
static __device__ __forceinline__ float tanh_s(float x) {
    float a = fabsf(x);
    float e = __expf(-2.f * a);
    float r = (1.f - e) * __builtin_amdgcn_rcpf(1.f + e);
    return copysignf(r, x);
}
// f16-pair pack/unpack for register-resident weights
static __device__ __forceinline__ unsigned pkf(float lo, float hi) {
    return ((unsigned)__half_as_ushort(__float2half(hi)) << 16) |
           (unsigned)__half_as_ushort(__float2half(lo));
}
static __device__ __forceinline__ float pklo(unsigned u) {
    return __half2float(__ushort_as_half((unsigned short)(u & 0xffffu)));
}
static __device__ __forceinline__ float pkhi(unsigned u) {
    return __half2float(__ushort_as_half((unsigned short)(u >> 16)));
}
// packed comm word: {tag16 (hi) | bf16 h bits (lo)}; u64 = 2 entries
static __device__ __forceinline__ bool chk2(unsigned long long v, unsigned want) {
    return (((unsigned)(v >> 16) & 0xffffu) == want) & ((unsigned)(v >> 48) == want);
}
static __device__ __forceinline__ float2 cvt2(unsigned long long v) {
    float2 r;
    r.x = __uint_as_float(((unsigned)v & 0xffffu) << 16);
    r.y = __uint_as_float(((unsigned)(v >> 32) & 0xffffu) << 16);
    return r;
}

// ---------------- embedding gather -> bf16 ----------------
__global__ __launch_bounds__(128) void embed_kernel(
    const int* __restrict__ tok, const float* __restrict__ emb,
    unsigned short* __restrict__ xs_b) {
    int t = blockIdx.x;
    int e4 = threadIdx.x;
    const float4* src = (const float4*)(emb + (size_t)tok[t] * EE);
    float4 v = src[e4];
    ushort4 o;
    o.x = f2b(v.x); o.y = f2b(v.y); o.z = f2b(v.z); o.w = f2b(v.w);
    ((ushort4*)(xs_b + (size_t)t * EE))[e4] = o;
}

// ---------------- generic f32 -> bf16 ----------------
__global__ __launch_bounds__(256) void f32_to_bf16(
    const float* __restrict__ in, unsigned short* __restrict__ out, long n4) {
    long i = (long)blockIdx.x * blockDim.x + threadIdx.x;
    long stride = (long)gridDim.x * blockDim.x;
    for (; i < n4; i += stride) {
        float4 v = ((const float4*)in)[i];
        ushort4 o;
        o.x = f2b(v.x); o.y = f2b(v.y); o.z = f2b(v.z); o.w = f2b(v.w);
        ((ushort4*)out)[i] = o;
    }
}

// ---------------- bf16 MFMA GEMM: C[M,N] = A[M,K] * B[N,K]^T + bias ----------------
__global__ __launch_bounds__(256) void gemm_bf16_nt(
    const unsigned short* __restrict__ A,   // [M][K] bf16 bits
    const unsigned short* __restrict__ B,   // [N][K] bf16 bits
    const float* __restrict__ bias1,        // [N] or null
    const float* __restrict__ bias2,        // [N] or null
    float* __restrict__ C,                  // [M][N]
    int K, int N) {
    __shared__ unsigned short ldsA[128 * 64];
    __shared__ unsigned short ldsB[128 * 64];
    const int tid = threadIdx.x;
    const int l = tid & 63;
    const int w = tid >> 6;
    const int wm = (w >> 1) * 64;
    const int wn = (w & 1) * 64;
    const int bm = blockIdx.y, bn = blockIdx.x;
    const size_t a_base = (size_t)bm * 128 * K;
    const size_t b_base = (size_t)bn * 128 * K;
    const int srow = tid >> 3;
    const int skc = tid & 7;

    f32x4 acc[4][4];
    for (int i = 0; i < 4; ++i)
        for (int j = 0; j < 4; ++j)
            acc[i][j] = (f32x4){0.f, 0.f, 0.f, 0.f};

    for (int kt = 0; kt < K; kt += 64) {
        uint4 av[4], bv[4];
#pragma unroll
        for (int i = 0; i < 4; ++i) {
            int row = srow + i * 32;
            av[i] = ((const uint4*)(A + a_base + (size_t)row * K + kt))[skc];
            bv[i] = ((const uint4*)(B + b_base + (size_t)row * K + kt))[skc];
        }
        __syncthreads();
#pragma unroll
        for (int i = 0; i < 4; ++i) {
            int row = srow + i * 32;
            int off = row * 128 + ((skc * 16) ^ ((row & 7) << 4));
            *(uint4*)((char*)ldsA + off) = av[i];
            *(uint4*)((char*)ldsB + off) = bv[i];
        }
        __syncthreads();
#pragma unroll
        for (int ks = 0; ks < 2; ++ks) {
            bf16x8 af[4], bfr[4];
            int kb = ks * 64 + (l >> 4) * 16;
#pragma unroll
            for (int f = 0; f < 4; ++f) {
                int ar = wm + f * 16 + (l & 15);
                af[f] = *(const bf16x8*)((const char*)ldsA + ar * 128 + (kb ^ ((ar & 7) << 4)));
                int br = wn + f * 16 + (l & 15);
                bfr[f] = *(const bf16x8*)((const char*)ldsB + br * 128 + (kb ^ ((br & 7) << 4)));
            }
#pragma unroll
            for (int fm = 0; fm < 4; ++fm)
#pragma unroll
                for (int fn = 0; fn < 4; ++fn)
                    acc[fm][fn] = __builtin_amdgcn_mfma_f32_16x16x32_bf16(
                        af[fm], bfr[fn], acc[fm][fn], 0, 0, 0);
        }
    }
    const int r0 = (l >> 4) * 4, cn = (l & 15);
#pragma unroll
    for (int fm = 0; fm < 4; ++fm)
#pragma unroll
        for (int fn = 0; fn < 4; ++fn) {
            int col = bn * 128 + wn + fn * 16 + cn;
            float bb = (bias1 ? bias1[col] : 0.f) + (bias2 ? bias2[col] : 0.f);
#pragma unroll
            for (int r = 0; r < 4; ++r) {
                int rowg = bm * 128 + wm + fm * 16 + r0 + r;
                C[(size_t)rowg * N + col] = acc[fm][fn][r] + bb;
            }
        }
}

// ======== macros for the recurrence kernel ========
#define PUBLISH(PTR, PK)                                                    \
    asm volatile("global_store_dword %0, %1, off sc0 sc1"                   \
                 :: "v"(PTR), "v"(PK) : "memory")
#define RED(D) { D += __shfl_xor(D, 32); D += __shfl_xor(D, 16);            \
                 D += __shfl_xor(D, 8);  D += __shfl_xor(D, 4);             \
                 D += __shfl_xor(D, 2);  D += __shfl_xor(D, 1); }
#define LDSREAD(H0, H1, H2, H3, BUF) {                                      \
    H0 = *(const float4*)&(BUF)[4 * lane];                                  \
    H1 = *(const float4*)&(BUF)[256 + 4 * lane];                            \
    H2 = *(const float4*)&(BUF)[512 + 4 * lane];                            \
    H3 = *(const float4*)&(BUF)[768 + 4 * lane]; }

// ---- register-resident weight row: 8 packed-f16-pair u32 per 64 owned elems ----
#define PK_DECL(P) unsigned P##_0,P##_1,P##_2,P##_3,P##_4,P##_5,P##_6,P##_7
#define PK_LOAD(P, RP) {                                                    \
    float4 t0_ = *(const float4*)(RP);                                      \
    float4 t1_ = *(const float4*)((RP) + 256);                              \
    float4 t2_ = *(const float4*)((RP) + 512);                              \
    float4 t3_ = *(const float4*)((RP) + 768);                              \
    P##_0 = pkf(t0_.x, t0_.y); P##_1 = pkf(t0_.z, t0_.w);                   \
    P##_2 = pkf(t1_.x, t1_.y); P##_3 = pkf(t1_.z, t1_.w);                   \
    P##_4 = pkf(t2_.x, t2_.y); P##_5 = pkf(t2_.z, t2_.w);                   \
    P##_6 = pkf(t3_.x, t3_.y); P##_7 = pkf(t3_.z, t3_.w); }
#define PK_PIN(P) asm volatile("" :                                         \
    "+v"(P##_0),"+v"(P##_1),"+v"(P##_2),"+v"(P##_3),                        \
    "+v"(P##_4),"+v"(P##_5),"+v"(P##_6),"+v"(P##_7))
#define PK_DOT(D, P, H0, H1, H2, H3) {                                      \
    D=__builtin_fmaf(pklo(P##_0),(H0).x,D); D=__builtin_fmaf(pkhi(P##_0),(H0).y,D); \
    D=__builtin_fmaf(pklo(P##_1),(H0).z,D); D=__builtin_fmaf(pkhi(P##_1),(H0).w,D); \
    D=__builtin_fmaf(pklo(P##_2),(H1).x,D); D=__builtin_fmaf(pkhi(P##_2),(H1).y,D); \
    D=__builtin_fmaf(pklo(P##_3),(H1).z,D); D=__builtin_fmaf(pkhi(P##_3),(H1).w,D); \
    D=__builtin_fmaf(pklo(P##_4),(H2).x,D); D=__builtin_fmaf(pkhi(P##_4),(H2).y,D); \
    D=__builtin_fmaf(pklo(P##_5),(H2).z,D); D=__builtin_fmaf(pkhi(P##_5),(H2).w,D); \
    D=__builtin_fmaf(pklo(P##_6),(H3).x,D); D=__builtin_fmaf(pkhi(P##_6),(H3).y,D); \
    D=__builtin_fmaf(pklo(P##_7),(H3).z,D); D=__builtin_fmaf(pkhi(P##_7),(H3).w,D); }

// ---------------- fused 2-layer pipelined LSTM recurrence ----------------
// 256 blocks x 512 threads. Blocks 0..127: layer 0; 128..255: layer 1.
// Comm: 64-slot rings of packed {tag16|bf16}; tag = step+1 (equality match).
// DIRECT per-thread u64 poll (r1's fast path) -> parity LDS -> ONE barrier.
// Deadlock-free by single-scalar back-pressure: L1 block 128 publishes its
// completed-step count `prog`; an L0 wave publishing step t first waits for
// prog >= t-HSLOT+2. Proof: prog=P => block128/wave0 passed its step-(P-1)
// h1-poll => ALL L1 waves published step P-2 => none still polling hist0
// step <= P-2; L0's write of slot t&MSK kills step t-HSLOT => need
// t-HSLOT <= P-2. L1 can always advance to L0's frontier => no cycle.
__attribute__((amdgpu_waves_per_eu(2, 2)))
__global__ __launch_bounds__(512) void lstm_fused(
    const float* __restrict__ Whh0,           // [4H][H]
    const float* __restrict__ pre0,           // [T][4H] (x-proj + both biases)
    const float* __restrict__ Wih1,           // [4H][H]
    const float* __restrict__ Whh1,           // [4H][H]
    const float* __restrict__ bih1,           // [4H]
    const float* __restrict__ bhh1,           // [4H]
    unsigned* __restrict__ hist0,             // [HSLOT][H] packed h0 ring
    unsigned* __restrict__ hist1,             // [HSLOT][H] packed h1 ring
    unsigned* __restrict__ prog,              // L1 progress scalar
    unsigned short* __restrict__ y1b,         // [T][H] bf16 layer-1 output
    float* __restrict__ hfb,                  // out + T*V      (h stack [2][H])
    float* __restrict__ cfb) {                // out + T*V + 2H (c stack [2][H])
    const int tid  = threadIdx.x;
    const int wv   = tid >> 6;
    const int lane = tid & 63;

    __shared__ float hA[2][HH];
    __shared__ float hB[2][HH];

    float4 h0_, h1_, h2_, h3_;

    if (blockIdx.x < 128) {
        // ================= layer 0 =================
        const int j = blockIdx.x * 8 + wv;
        PK_DECL(wI); PK_DECL(wF); PK_DECL(wG); PK_DECL(wO);
        PK_LOAD(wI, Whh0 + (size_t)(0 * HH + j) * HH + 4 * lane);
        PK_LOAD(wF, Whh0 + (size_t)(1 * HH + j) * HH + 4 * lane);
        PK_LOAD(wG, Whh0 + (size_t)(2 * HH + j) * HH + 4 * lane);
        PK_LOAD(wO, Whh0 + (size_t)(3 * HH + j) * HH + 4 * lane);
        PK_PIN(wI); PK_PIN(wF); PK_PIN(wG); PK_PIN(wO);

        float c = 0.f;
        float px0 = pre0[0 * HH + j], px1 = pre0[1 * HH + j];
        float px2 = pre0[2 * HH + j], px3 = pre0[3 * HH + j];

        for (int t = 0; t < TT; ++t) {
            float nx0 = 0.f, nx1 = 0.f, nx2 = 0.f, nx3 = 0.f;
            if (t + 1 < TT) {
                const float* pp = pre0 + (size_t)(t + 1) * 4 * HH + j;
                nx0 = pp[0]; nx1 = pp[HH]; nx2 = pp[2 * HH]; nx3 = pp[3 * HH];
            }
            const int par = t & 1;
            if (t > 0) {
                const unsigned long long* src =
                    (const unsigned long long*)(hist0 + (size_t)((t - 1) & HMSK) * HH);
                const unsigned want = (unsigned)t;
                unsigned long long v;
                for (;;) {
                    v = __hip_atomic_load(src + tid, __ATOMIC_RELAXED, __HIP_MEMORY_SCOPE_AGENT);
                    if (chk2(v, want)) break;
                    __builtin_amdgcn_s_sleep(1);
                }
                *(float2*)&hA[par][2 * tid] = cvt2(v);
            } else {
                *(float2*)&hA[par][2 * tid] = make_float2(0.f, 0.f);
            }
            __syncthreads();
            float d0 = 0.f, d1 = 0.f, d2 = 0.f, d3 = 0.f;
            if (t > 0) {
                LDSREAD(h0_, h1_, h2_, h3_, hA[par]);
                PK_DOT(d0, wI, h0_, h1_, h2_, h3_);
                PK_DOT(d1, wF, h0_, h1_, h2_, h3_);
                PK_DOT(d2, wG, h0_, h1_, h2_, h3_);
                PK_DOT(d3, wO, h0_, h1_, h2_, h3_);
                RED(d0); RED(d1); RED(d2); RED(d3);
            }
            float i_ = sigm(px0 + d0), f_ = sigm(px1 + d1);
            float g_ = tanh_s(px2 + d2), o_ = sigm(px3 + d3);
            c = f_ * c + i_ * g_;
            float h = o_ * tanh_s(c);
            if (lane == 0) {
                if (t >= HSLOT) {   // back-pressure: see header proof
                    const unsigned limit = (unsigned)(t - HSLOT + 2);
                    while (__hip_atomic_load(prog, __ATOMIC_RELAXED,
                                             __HIP_MEMORY_SCOPE_AGENT) < limit)
                        __builtin_amdgcn_s_sleep(1);
                }
                unsigned pack = ((unsigned)(t + 1) << 16) | (unsigned)f2b(h);
                PUBLISH(hist0 + (size_t)(t & HMSK) * HH + j, pack);
                if (t == TT - 1) { hfb[j] = h; cfb[j] = c; }
            }
            px0 = nx0; px1 = nx1; px2 = nx2; px3 = nx3;
        }
    } else {
        // ================= layer 1 (1 step behind) =================
        const int j = (blockIdx.x - 128) * 8 + wv;
        PK_DECL(iI); PK_DECL(iF); PK_DECL(iG); PK_DECL(iO);
        PK_DECL(hI); PK_DECL(hF); PK_DECL(hG); PK_DECL(hO);
        PK_LOAD(iI, Wih1 + (size_t)(0 * HH + j) * HH + 4 * lane);
        PK_LOAD(iF, Wih1 + (size_t)(1 * HH + j) * HH + 4 * lane);
        PK_LOAD(iG, Wih1 + (size_t)(2 * HH + j) * HH + 4 * lane);
        PK_LOAD(iO, Wih1 + (size_t)(3 * HH + j) * HH + 4 * lane);
        PK_LOAD(hI, Whh1 + (size_t)(0 * HH + j) * HH + 4 * lane);
        PK_LOAD(hF, Whh1 + (size_t)(1 * HH + j) * HH + 4 * lane);
        PK_LOAD(hG, Whh1 + (size_t)(2 * HH + j) * HH + 4 * lane);
        PK_LOAD(hO, Whh1 + (size_t)(3 * HH + j) * HH + 4 * lane);
        PK_PIN(iI); PK_PIN(iF); PK_PIN(iG); PK_PIN(iO);
        PK_PIN(hI); PK_PIN(hF); PK_PIN(hG); PK_PIN(hO);
        float bs0 = bih1[0 * HH + j] + bhh1[0 * HH + j];
        float bs1 = bih1[1 * HH + j] + bhh1[1 * HH + j];
        float bs2 = bih1[2 * HH + j] + bhh1[2 * HH + j];
        float bs3 = bih1[3 * HH + j] + bhh1[3 * HH + j];

        float c = 0.f;
        for (int t = 0; t < TT; ++t) {
            const int par = t & 1;
            {
                const unsigned long long* srcA =
                    (const unsigned long long*)(hist0 + (size_t)(t & HMSK) * HH);
                const unsigned long long* srcB =
                    (const unsigned long long*)(hist1 + (size_t)((t - 1) & HMSK) * HH);
                const unsigned wA = (unsigned)(t + 1), wB = (unsigned)t;
                unsigned long long vA = 0, vB = 0;
                bool rA = false, rB = (t == 0);
                for (;;) {
                    if (!rA) { vA = __hip_atomic_load(srcA + tid, __ATOMIC_RELAXED, __HIP_MEMORY_SCOPE_AGENT); rA = chk2(vA, wA); }
                    if (!rB) { vB = __hip_atomic_load(srcB + tid, __ATOMIC_RELAXED, __HIP_MEMORY_SCOPE_AGENT); rB = chk2(vB, wB); }
                    if (rA & rB) break;
                    __builtin_amdgcn_s_sleep(1);
                }
                *(float2*)&hA[par][2 * tid] = cvt2(vA);
                *(float2*)&hB[par][2 * tid] = (t > 0) ? cvt2(vB) : make_float2(0.f, 0.f);
            }
            __syncthreads();
            float d0 = 0.f, d1 = 0.f, d2 = 0.f, d3 = 0.f;
            LDSREAD(h0_, h1_, h2_, h3_, hA[par]);
            PK_DOT(d0, iI, h0_, h1_, h2_, h3_);
            PK_DOT(d1, iF, h0_, h1_, h2_, h3_);
            PK_DOT(d2, iG, h0_, h1_, h2_, h3_);
            PK_DOT(d3, iO, h0_, h1_, h2_, h3_);
            LDSREAD(h0_, h1_, h2_, h3_, hB[par]);
            PK_DOT(d0, hI, h0_, h1_, h2_, h3_);
            PK_DOT(d1, hF, h0_, h1_, h2_, h3_);
            PK_DOT(d2, hG, h0_, h1_, h2_, h3_);
            PK_DOT(d3, hO, h0_, h1_, h2_, h3_);
            RED(d0); RED(d1); RED(d2); RED(d3);
            float i_ = sigm(bs0 + d0), f_ = sigm(bs1 + d1);
            float g_ = tanh_s(bs2 + d2), o_ = sigm(bs3 + d3);
            c = f_ * c + i_ * g_;
            float h = o_ * tanh_s(c);
            if (lane == 0) {
                unsigned short hb16 = f2b(h);
                unsigned pack = ((unsigned)(t + 1) << 16) | (unsigned)hb16;
                PUBLISH(hist1 + (size_t)(t & HMSK) * HH + j, pack);
                y1b[(size_t)t * HH + j] = hb16;
                if (t == TT - 1) { hfb[HH + j] = h; cfb[HH + j] = c; }
            }
            if (blockIdx.x == 128 && tid == 0)
                __hip_atomic_store(prog, (unsigned)(t + 1),
                                   __ATOMIC_RELAXED, __HIP_MEMORY_SCOPE_AGENT);
        }
    }
}

// ---------------- row softmax over V=32000, in place ----------------
__global__ __launch_bounds__(256) void softmax_kernel(float* __restrict__ data) {
    const int row = blockIdx.x;
    const int tid = threadIdx.x;
    float* p = data + (size_t)row * VV;
    float m = -1e30f, s = 0.f;
    for (int i = tid * 4; i < VV; i += 1024) {
        float4 v = *(const float4*)(p + i);
        float x[4] = {v.x, v.y, v.z, v.w};
#pragma unroll
        for (int q = 0; q < 4; ++q) {
            float xv = x[q];
            if (xv > m) { s = s * __expf(m - xv) + 1.f; m = xv; }
            else s += __expf(xv - m);
        }
    }
#pragma unroll
    for (int off = 32; off; off >>= 1) {
        float mo = __shfl_xor(m, off);
        float so = __shfl_xor(s, off);
        float mn = fmaxf(m, mo);
        s = s * __expf(m - mn) + so * __expf(mo - mn);
        m = mn;
    }
    __shared__ float sm[4], ss[4];
    int wvv = tid >> 6;
    if ((tid & 63) == 0) { sm[wvv] = m; ss[wvv] = s; }
    __syncthreads();
    float M = fmaxf(fmaxf(sm[0], sm[1]), fmaxf(sm[2], sm[3]));
    float S = ss[0] * __expf(sm[0] - M) + ss[1] * __expf(sm[1] - M) +
              ss[2] * __expf(sm[2] - M) + ss[3] * __expf(sm[3] - M);
    float inv = 1.f / S;
    for (int i = tid * 4; i < VV; i += 1024) {
        float4 v = *(const float4*)(p + i);
        v.x = __expf(v.x - M) * inv;
        v.y = __expf(v.y - M) * inv;
        v.z = __expf(v.z - M) * inv;
        v.w = __expf(v.w - M) * inv;
        *(float4*)(p + i) = v;
    }
}

extern "C" void kernel_launch(void* const* d_in, const int* in_sizes, int n_in,
                              void* d_out, int out_size, void* d_ws, size_t ws_size,
                              hipStream_t stream) {
    const int*   inputs = (const int*)d_in[0];
    const float* emb    = (const float*)d_in[1];
    const float* w_ih0  = (const float*)d_in[2];
    const float* w_hh0  = (const float*)d_in[3];
    const float* b_ih0  = (const float*)d_in[4];
    const float* b_hh0  = (const float*)d_in[5];
    const float* w_ih1  = (const float*)d_in[6];
    const float* w_hh1  = (const float*)d_in[7];
    const float* b_ih1  = (const float*)d_in[8];
    const float* b_hh1  = (const float*)d_in[9];
    const float* w_out  = (const float*)d_in[10];
    const float* b_out  = (const float*)d_in[11];
    float* out = (float*)d_out;

    char* ws = (char*)d_ws;
    size_t off = 0;
    auto alloc = [&](size_t bytes) -> void* {
        void* p = ws + off;
        off += (bytes + 255) & ~(size_t)255;
        return p;
    };
    float* pre0          = (float*)alloc((size_t)TT * 4 * HH * 4);
    unsigned short* xsb  = (unsigned short*)alloc((size_t)TT * EE * 2);
    unsigned short* w0b  = (unsigned short*)alloc((size_t)4 * HH * EE * 2);
    unsigned short* wob  = (unsigned short*)alloc((size_t)VV * HH * 2);
    unsigned short* y1b  = (unsigned short*)alloc((size_t)TT * HH * 2);
    unsigned* hist0      = (unsigned*)alloc((size_t)HSLOT * HH * 4);
    unsigned* hist1      = (unsigned*)alloc((size_t)HSLOT * HH * 4);
    unsigned* prog       = (unsigned*)alloc(256);
    if (off > ws_size) return;

    (void)hipMemsetAsync(hist0, 0, (size_t)HSLOT * HH * 4, stream);
    (void)hipMemsetAsync(hist1, 0, (size_t)HSLOT * HH * 4, stream);
    (void)hipMemsetAsync(prog, 0, 256, stream);

    embed_kernel<<<TT, 128, 0, stream>>>(inputs, emb, xsb);
    f32_to_bf16<<<1024, 256, 0, stream>>>(w_ih0, w0b, (long)4 * HH * EE / 4);
    f32_to_bf16<<<2048, 256, 0, stream>>>(w_out, wob, (long)VV * HH / 4);

    // pre0 = xs @ w_ih0^T + b_ih0 + b_hh0
    gemm_bf16_nt<<<dim3(4 * HH / 128, TT / 128), 256, 0, stream>>>(
        xsb, w0b, b_ih0, b_hh0, pre0, EE, 4 * HH);

    // fused pipelined 2-layer recurrence
    lstm_fused<<<256, 512, 0, stream>>>(
        w_hh0, pre0, w_ih1, w_hh1, b_ih1, b_hh1,
        hist0, hist1, prog, y1b,
        out + (size_t)TT * VV, out + (size_t)TT * VV + 2 * HH);

    // logits = ys1 @ w_out^T + b_out  (into d_out, softmax in place after)
    gemm_bf16_nt<<<dim3(VV / 128, TT / 128), 256, 0, stream>>>(
        y1b, wob, b_out, nullptr, out, HH, VV);
    softmax_kernel<<<TT, 256, 0, stream>>>(out);
}